// Round 10
// baseline (11866.943 us; speedup 1.0000x reference)
//
#include <hip/hip_runtime.h>
#include <hip/hip_bf16.h>

#define BB 512     // batch
#define TT 96      // encoder steps
#define PP 96      // decoder steps
#define EE 321     // input features
#define CC 321     // output channels
#define HH 512     // hidden
#define G4 2048    // 4*H
#define EPAD 352   // 321 padded to 32
#define NFC 384    // fc N pad (64-multiple)

// fc_batch (2-deep) staging
#define BUF_SZ 24576
#define XH_OFF 0
#define XL_OFF 8192
#define WH_OFF 16384
#define WL_OFF 20480
#define FC_SMEM 49152

// lstm kernels: LDS = gate-exchange scratch only (64 x 68 fp32)
#define SG_SMEM 17408

typedef unsigned short u16;
typedef __attribute__((ext_vector_type(8))) short bf16x8;
typedef __attribute__((ext_vector_type(16))) float floatx16;

__device__ __forceinline__ void splitf(float v, u16& h, u16& l){
  __hip_bfloat16 bh = __float2bfloat16(v);
  h = *reinterpret_cast<u16*>(&bh);
  float r = v - __bfloat162float(bh);
  __hip_bfloat16 bl = __float2bfloat16(r);
  l = *reinterpret_cast<u16*>(&bl);
}

// async global->LDS (fc_batch only)
__device__ __forceinline__ void gload16(const void* g, void* l){
  __builtin_amdgcn_global_load_lds((const __attribute__((address_space(1))) void*)g,
                                   (__attribute__((address_space(3))) void*)l, 16, 0, 0);
}

// ---------- fused prep ----------
struct SJob { const float* src; u16* hi; u16* lo; int rows, cols, rowspad, colspad; };
struct SJobs { SJob j[9]; };

__global__ void split_multi(SJobs js){
  const int stride = gridDim.x * blockDim.x;
  const int t0 = blockIdx.x * blockDim.x + threadIdx.x;
  for (int k = 0; k < 9; ++k){
    const SJob J = js.j[k];
    const int total = J.rowspad * J.colspad;
    for (int idx = t0; idx < total; idx += stride){
      int r = idx / J.colspad, cc = idx - r * J.colspad;
      float v = (r < J.rows && cc < J.cols) ? J.src[(size_t)r * J.cols + cc] : 0.f;
      u16 h, l; splitf(v, h, l);
      J.hi[idx] = h; J.lo[idx] = l;
    }
  }
}

// Wcomb = Wd0ih @ fcW, split to bf16 hi/lo directly; bd0c = (d_bih0+d_bhh0) + Wd0ih @ fcb
__global__ void wcomb_fused(const float* __restrict__ A,
                            const float* __restrict__ Bm,
                            const float* __restrict__ bih, const float* __restrict__ bhh,
                            const float* __restrict__ fcb,
                            u16* __restrict__ Wc_h, u16* __restrict__ Wc_l,
                            float* __restrict__ bd0c){
  __shared__ float arow[EE];
  __shared__ float red[256];
  const int g = blockIdx.x;
  for (int e = threadIdx.x; e < EE; e += 256) arow[e] = A[(size_t)g * EE + e];
  __syncthreads();
  float ps = 0.f;
  for (int e = threadIdx.x; e < EE; e += 256) ps += arow[e] * fcb[e];
  red[threadIdx.x] = ps; __syncthreads();
  for (int s = 128; s > 0; s >>= 1){
    if (threadIdx.x < s) red[threadIdx.x] += red[threadIdx.x + s];
    __syncthreads();
  }
  if (threadIdx.x == 0) bd0c[g] = bih[g] + bhh[g] + red[0];
  for (int k = threadIdx.x; k < HH; k += 256){
    float s = 0.f;
    for (int e = 0; e < EE; ++e) s += arow[e] * Bm[(size_t)e * HH + k];
    u16 h, l; splitf(s, h, l);
    Wc_h[(size_t)g * HH + k] = h; Wc_l[(size_t)g * HH + k] = l;
  }
}

__global__ void prep_misc(
    const float* e_bih0, const float* e_bhh0, float* be0,
    const float* e_bih1, const float* e_bhh1, float* be1,
    const float* d_bih0, const float* d_bhh0, float* bd0,
    const float* d_bih1, const float* d_bhh1, float* bd1,
    const float* fc_b, float* bfc,
    const float* x_enc, u16* inph, u16* inpl, u16* xh, u16* xl){
  const int stride = gridDim.x * blockDim.x;
  const int t0 = blockIdx.x * blockDim.x + threadIdx.x;
  for (int i = t0; i < G4; i += stride){
    be0[i] = e_bih0[i] + e_bhh0[i];
    be1[i] = e_bih1[i] + e_bhh1[i];
    bd0[i] = d_bih0[i] + d_bhh0[i];
    bd1[i] = d_bih1[i] + d_bhh1[i];
  }
  for (int i = t0; i < NFC; i += stride) bfc[i] = (i < CC) ? fc_b[i] : 0.f;
  for (int idx = t0; idx < BB * EPAD; idx += stride){
    int b = idx / EPAD, j = idx - b * EPAD;
    float v = (j < EE) ? x_enc[(size_t)b * TT * EE + (size_t)(TT - 1) * EE + j] : 0.f;
    u16 h, l; splitf(v, h, l);
    inph[idx] = h; inpl[idx] = l;
  }
  for (int idx = t0; idx < TT * BB * EPAD; idx += stride){
    int e = idx % EPAD;
    int rest = idx / EPAD;
    int b = rest % BB;
    int t = rest / BB;
    float v = (e < EE) ? x_enc[((size_t)b * TT + t) * EE + e] : 0.f;
    u16 h, l; splitf(v, h, l);
    xh[idx] = h; xl[idx] = l;
  }
}

// ---------- register-staged M=64 x N=64 GEMM: no LDS, no barriers in K-loop ----------
// Each wave loads ITS OWN MFMA fragments straight to VGPRs (no cross-wave sharing needed).
// A row = m0 + wm*32 + ml ; B row (gate-remap) = (brw>>4)*HH + u0 + (brw&15).
// 16B k-slot t0 = kk2*2 + thalf at element offset t0*8 — identical operands/order to the
// proven LDS path => bit-identical accumulation.
struct F8 { bf16x8 ah0, ah1, al0, al1, bh0, bh1, bl0, bl1; };

__device__ __forceinline__ void mfma6(floatx16& acc, const F8& f){
  acc = __builtin_amdgcn_mfma_f32_32x32x16_bf16(f.ah0, f.bh0, acc, 0, 0, 0);
  acc = __builtin_amdgcn_mfma_f32_32x32x16_bf16(f.ah0, f.bl0, acc, 0, 0, 0);
  acc = __builtin_amdgcn_mfma_f32_32x32x16_bf16(f.al0, f.bh0, acc, 0, 0, 0);
  acc = __builtin_amdgcn_mfma_f32_32x32x16_bf16(f.ah1, f.bh1, acc, 0, 0, 0);
  acc = __builtin_amdgcn_mfma_f32_32x32x16_bf16(f.ah1, f.bl1, acc, 0, 0, 0);
  acc = __builtin_amdgcn_mfma_f32_32x32x16_bf16(f.al1, f.bh1, acc, 0, 0, 0);
}

// dual-phase (ih then hh) when Hph != null; single-phase otherwise.
__device__ __forceinline__ floatx16 gemm64(
    int m0, int u0,
    const u16* __restrict__ Xh, const u16* __restrict__ Xl, int K1pad,
    const u16* __restrict__ W1h, const u16* __restrict__ W1l,
    const u16* __restrict__ Whh_h, const u16* __restrict__ Whh_l,
    const u16* __restrict__ Hph, const u16* __restrict__ Hpl)
{
  const int lane = threadIdx.x & 63;
  const int wid  = threadIdx.x >> 6;
  const int wm = wid >> 1, wn = wid & 1;
  const int ml = lane & 31, thalf = lane >> 5;
  const size_t arow = (size_t)(m0 + wm * 32 + ml);
  const int brw = wn * 32 + ml;
  const size_t wrow = (size_t)(brw >> 4) * HH + u0 + (brw & 15);
  const int nch1 = K1pad >> 5;
  const int ncht = Hph ? nch1 + (HH >> 5) : nch1;   // >= 11 always

  floatx16 acc = {0.f,0.f,0.f,0.f,0.f,0.f,0.f,0.f,0.f,0.f,0.f,0.f,0.f,0.f,0.f,0.f};
  F8 fA, fB, fC;

  auto LD = [&](F8& f, int ch){
    const bool p1 = ch < nch1;
    const int k0 = (p1 ? ch : ch - nch1) << 5;
    const u16* xh = p1 ? Xh : Hph;
    const u16* xl = p1 ? Xl : Hpl;
    const u16* wh = p1 ? W1h : Whh_h;
    const u16* wl = p1 ? W1l : Whh_l;
    const size_t Kp = p1 ? (size_t)K1pad : (size_t)HH;
    const size_t xo = arow * Kp + k0 + thalf * 8;
    const size_t wo = wrow * Kp + k0 + thalf * 8;
    f.ah0 = *(const bf16x8*)(xh + xo);
    f.ah1 = *(const bf16x8*)(xh + xo + 16);   // k-slot 2+thalf
    f.al0 = *(const bf16x8*)(xl + xo);
    f.al1 = *(const bf16x8*)(xl + xo + 16);
    f.bh0 = *(const bf16x8*)(wh + wo);
    f.bh1 = *(const bf16x8*)(wh + wo + 16);
    f.bl0 = *(const bf16x8*)(wl + wo);
    f.bl1 = *(const bf16x8*)(wl + wo + 16);
  };

  // 3-deep software pipeline, static register rotation (no runtime-indexed arrays)
  LD(fA, 0); LD(fB, 1);
  for (int c = 0; c < ncht; c += 3){
    if (c + 2 < ncht) LD(fC, c + 2);
    mfma6(acc, fA);                 // chunk c
    if (c + 1 >= ncht) break;
    if (c + 3 < ncht) LD(fA, c + 3);
    mfma6(acc, fB);                 // chunk c+1
    if (c + 2 >= ncht) break;
    if (c + 4 < ncht) LD(fB, c + 4);
    mfma6(acc, fC);                 // chunk c+2
  }
  return acc;
}

// cell-finish epilogue: gate exchange via LDS (sole LDS use), cell update, split h-write
__device__ __forceinline__ void fin_epi(char* smem, const floatx16& acc, int m0, int u0,
    const float* __restrict__ bias, const float* __restrict__ Gin,
    u16* __restrict__ Hnh, u16* __restrict__ Hnl, float* __restrict__ cst)
{
  float (*sG)[68] = (float (*)[68])smem;
  const int tid = threadIdx.x, lane = tid & 63, wid = tid >> 6;
  const int wm = wid >> 1, wn = wid & 1, ml = lane & 31, thalf = lane >> 5;
  #pragma unroll
  for (int r = 0; r < 16; ++r){
    const int mm = (r & 3) + 8 * (r >> 2) + 4 * thalf;
    sG[wm * 32 + mm][wn * 32 + ml] = acc[r];
  }
  __syncthreads();
  for (int e = tid; e < 1024; e += 256){
    const int m = e >> 4, u = e & 15;
    const int gj = u0 + u;
    float gi = sG[m][u]      + bias[gj];
    float gf = sG[m][16 + u] + bias[HH + gj];
    float gg = sG[m][32 + u] + bias[2 * HH + gj];
    float go = sG[m][48 + u] + bias[3 * HH + gj];
    if (Gin){
      const float* gb = Gin + (size_t)(m0 + m) * G4;
      gi += gb[gj]; gf += gb[HH + gj]; gg += gb[2 * HH + gj]; go += gb[3 * HH + gj];
    }
    const float si = 1.f / (1.f + expf(-gi));
    const float sf = 1.f / (1.f + expf(-gf));
    const float so = 1.f / (1.f + expf(-go));
    const size_t sidx = (size_t)(m0 + m) * HH + gj;
    const float cn = sf * cst[sidx] + si * tanhf(gg);
    const float hn = so * tanhf(cn);
    cst[sidx] = cn;
    u16 hh, hl; splitf(hn, hh, hl);
    Hnh[sidx] = hh; Hnl[sidx] = hl;
  }
}

// partial-gate store: Gout[b][gate*512+unit] = acc (fp32)
__device__ __forceinline__ void part_st(const floatx16& acc, float* __restrict__ Gout,
                                        int m0, int u0){
  const int tid = threadIdx.x, lane = tid & 63, wid = tid >> 6;
  const int wm = wid >> 1, wn = wid & 1, ml = lane & 31, thalf = lane >> 5;
  const int c = wn * 32 + ml;
  const size_t gcolo = (size_t)(c >> 4) * HH + u0 + (c & 15);
  #pragma unroll
  for (int r = 0; r < 16; ++r){
    const int mm = (r & 3) + 8 * (r >> 2) + 4 * thalf;
    Gout[(size_t)(m0 + wm * 32 + mm) * G4 + gcolo] = acc[r];
  }
}

// decoder combined launch: blocks [0,256) = cell-finish (single-phase K), [256,512) = partial GEMM
__global__ __launch_bounds__(256) void dec_ab(
    const u16* Xfh, const u16* Xfl, int Kf,
    const u16* Wf_h, const u16* Wf_l,
    const float* bias, const float* Gin,
    u16* Hnh, u16* Hnl, float* cst,
    const u16* Xph, const u16* Xpl,
    const u16* Wp_h, const u16* Wp_l,
    float* Gout)
{
  extern __shared__ char smem[];
  if (blockIdx.x < 256){
    const int bx = blockIdx.x;
    const int m0 = (bx >> 5) * 64, u0 = (bx & 31) * 16;
    floatx16 a = gemm64(m0, u0, Xfh, Xfl, Kf, Wf_h, Wf_l,
                        nullptr, nullptr, nullptr, nullptr);
    fin_epi(smem, a, m0, u0, bias, Gin, Hnh, Hnl, cst);
  } else {
    const int bx = blockIdx.x - 256;
    const int m0 = (bx >> 5) * 64, u0 = (bx & 31) * 16;
    floatx16 a = gemm64(m0, u0, Xph, Xpl, HH, Wp_h, Wp_l,
                        nullptr, nullptr, nullptr, nullptr);
    part_st(a, Gout, m0, u0);
  }
}

// Fused encoder step: blocks [0,256) = cell0(t), [256,512) = cell1(t-1). dual-phase K.
// At t==TT (act0==0, do_part==1) the idle cell0 half runs Gp0 = h0_final @ Wd0hh.
__global__ __launch_bounds__(256) void lstm_pair(
    int act0, const u16* X0h, const u16* X0l,
    const u16* W0ih_h, const u16* W0ih_l, const u16* W0hh_h, const u16* W0hh_l,
    const float* b0, const u16* H0ph, const u16* H0pl, u16* H0nh, u16* H0nl, float* c0,
    int act1, const u16* X1h, const u16* X1l,
    const u16* W1ih_h, const u16* W1ih_l, const u16* W1hh_h, const u16* W1hh_l,
    const float* b1, const u16* H1ph, const u16* H1pl, u16* H1nh, u16* H1nl, float* c1,
    int do_part, const u16* Wp_h, const u16* Wp_l, float* Gout)
{
  extern __shared__ char smem[];
  const int half = blockIdx.x >> 8;
  const int bx   = blockIdx.x & 255;
  const int m0 = (bx >> 5) * 64, u0 = (bx & 31) * 16;
  if (half == 0 && !act0){
    if (do_part){
      floatx16 a = gemm64(m0, u0, H0ph, H0pl, HH, Wp_h, Wp_l,
                          nullptr, nullptr, nullptr, nullptr);
      part_st(a, Gout, m0, u0);
    }
    return;
  }
  if (half == 1 && !act1) return;
  if (half == 0){
    floatx16 a = gemm64(m0, u0, X0h, X0l, EPAD, W0ih_h, W0ih_l,
                        W0hh_h, W0hh_l, H0ph, H0pl);
    fin_epi(smem, a, m0, u0, b0, nullptr, H0nh, H0nl, c0);
  } else {
    floatx16 a = gemm64(m0, u0, X1h, X1l, HH, W1ih_h, W1ih_l,
                        W1hh_h, W1hh_l, H1ph, H1pl);
    fin_epi(smem, a, m0, u0, b1, nullptr, H1nh, H1nl, c1);
  }
}

// ---------- batched FC over all decoder steps (unchanged, proven) ----------
__global__ __launch_bounds__(256) void fc_batch(
    const u16* __restrict__ Hh, const u16* __restrict__ Hl,
    const u16* __restrict__ Wh, const u16* __restrict__ Wl,
    const float* __restrict__ bfc,
    float* __restrict__ out)
{
  extern __shared__ char smem[];
  const int tid = threadIdx.x, lane = tid & 63, wid = tid >> 6;
  const int wm = wid >> 1, wn = wid & 1;
  const int m0 = blockIdx.x * 128;      // row = p*512 + b
  const int n0 = blockIdx.y * 64;

  floatx16 acc0 = {0.f,0.f,0.f,0.f,0.f,0.f,0.f,0.f,0.f,0.f,0.f,0.f,0.f,0.f,0.f,0.f};
  floatx16 acc1 = {0.f,0.f,0.f,0.f,0.f,0.f,0.f,0.f,0.f,0.f,0.f,0.f,0.f,0.f,0.f,0.f};

  const int ml    = lane & 31;
  const int thalf = lane >> 5;
  const int a0r = wm * 64 + ml;
  const int a1r = a0r + 32;
  const int brw = wn * 32 + ml;
  const int xa  = (a0r >> 1) & 3;
  const int xb  = (brw >> 1) & 3;

  const int sl  = lane & 3;
  const int rq  = lane >> 2;
  const int rx0 = wid * 32 + rq;
  const int rw  = wid * 16 + rq;
  const int sgx = (sl ^ ((rx0 >> 1) & 3)) << 4;
  const int sgw = (sl ^ ((rw  >> 1) & 3)) << 4;
  const size_t gxr0 = (size_t)(m0 + rx0);
  const size_t gxr1 = gxr0 + 16;
  const size_t gwr  = (size_t)(n0 + rw);
  const int oX = wid * 32 * 64;
  const int oW = wid * 16 * 64;

  auto stage = [&](int ch){
    const int k0 = ch << 5;
    char* b = smem + (ch & 1) * BUF_SZ;
    gload16((const char*)(Hh + gxr0 * HH + k0) + sgx, b + XH_OFF + oX);
    gload16((const char*)(Hh + gxr1 * HH + k0) + sgx, b + XH_OFF + oX + 1024);
    gload16((const char*)(Hl + gxr0 * HH + k0) + sgx, b + XL_OFF + oX);
    gload16((const char*)(Hl + gxr1 * HH + k0) + sgx, b + XL_OFF + oX + 1024);
    gload16((const char*)(Wh + gwr  * HH + k0) + sgw, b + WH_OFF + oW);
    gload16((const char*)(Wl + gwr  * HH + k0) + sgw, b + WL_OFF + oW);
  };

  stage(0);
  for (int ch = 0; ch < 16; ++ch){
    if (ch + 1 < 16) stage(ch + 1);
    __builtin_amdgcn_sched_barrier(0);
    if (ch + 1 < 16) { asm volatile("s_waitcnt vmcnt(6)" ::: "memory"); }
    else             { asm volatile("s_waitcnt vmcnt(0)" ::: "memory"); }
    __builtin_amdgcn_s_barrier();
    __builtin_amdgcn_sched_barrier(0);
    const char* bufc = smem + (ch & 1) * BUF_SZ;
    #pragma unroll
    for (int kk2 = 0; kk2 < 2; ++kk2){
      const int t0 = kk2 * 2 + thalf;
      bf16x8 ah0 = *(const bf16x8*)(bufc + XH_OFF + a0r * 64 + ((t0 ^ xa) << 4));
      bf16x8 al0 = *(const bf16x8*)(bufc + XL_OFF + a0r * 64 + ((t0 ^ xa) << 4));
      bf16x8 ah1 = *(const bf16x8*)(bufc + XH_OFF + a1r * 64 + ((t0 ^ xa) << 4));
      bf16x8 al1 = *(const bf16x8*)(bufc + XL_OFF + a1r * 64 + ((t0 ^ xa) << 4));
      bf16x8 bh  = *(const bf16x8*)(bufc + WH_OFF + brw * 64 + ((t0 ^ xb) << 4));
      bf16x8 bl  = *(const bf16x8*)(bufc + WL_OFF + brw * 64 + ((t0 ^ xb) << 4));
      acc0 = __builtin_amdgcn_mfma_f32_32x32x16_bf16(ah0, bh, acc0, 0, 0, 0);
      acc0 = __builtin_amdgcn_mfma_f32_32x32x16_bf16(ah0, bl, acc0, 0, 0, 0);
      acc0 = __builtin_amdgcn_mfma_f32_32x32x16_bf16(al0, bh, acc0, 0, 0, 0);
      acc1 = __builtin_amdgcn_mfma_f32_32x32x16_bf16(ah1, bh, acc1, 0, 0, 0);
      acc1 = __builtin_amdgcn_mfma_f32_32x32x16_bf16(ah1, bl, acc1, 0, 0, 0);
      acc1 = __builtin_amdgcn_mfma_f32_32x32x16_bf16(al1, bh, acc1, 0, 0, 0);
    }
    __builtin_amdgcn_sched_barrier(0);
    asm volatile("s_waitcnt lgkmcnt(0)" ::: "memory");
    __builtin_amdgcn_s_barrier();
    __builtin_amdgcn_sched_barrier(0);
  }

  const int n = n0 + wn * 32 + ml;
  if (n < CC){
    const float bv = bfc[n];
    #pragma unroll
    for (int r = 0; r < 16; ++r){
      const int mm = (r & 3) + 8 * (r >> 2) + 4 * thalf;
      {
        const int rr = m0 + wm * 64 + mm;
        out[(size_t)(rr & 511) * PP * CC + (size_t)(rr >> 9) * CC + n] = acc0[r] + bv;
      }
      {
        const int rr = m0 + wm * 64 + 32 + mm;
        out[(size_t)(rr & 511) * PP * CC + (size_t)(rr >> 9) * CC + n] = acc1[r] + bv;
      }
    }
  }
}

extern "C" void kernel_launch(void* const* d_in, const int* in_sizes, int n_in,
                              void* d_out, int out_size, void* d_ws, size_t ws_size,
                              hipStream_t stream) {
  const float* x_enc  = (const float*)d_in[0];
  const float* e_Wih0 = (const float*)d_in[4];
  const float* e_Whh0 = (const float*)d_in[5];
  const float* e_bih0 = (const float*)d_in[6];
  const float* e_bhh0 = (const float*)d_in[7];
  const float* e_Wih1 = (const float*)d_in[8];
  const float* e_Whh1 = (const float*)d_in[9];
  const float* e_bih1 = (const float*)d_in[10];
  const float* e_bhh1 = (const float*)d_in[11];
  const float* d_Wih0 = (const float*)d_in[12];
  const float* d_Whh0 = (const float*)d_in[13];
  const float* d_bih0 = (const float*)d_in[14];
  const float* d_bhh0 = (const float*)d_in[15];
  const float* d_Wih1 = (const float*)d_in[16];
  const float* d_Whh1 = (const float*)d_in[17];
  const float* d_bih1 = (const float*)d_in[18];
  const float* d_bhh1 = (const float*)d_in[19];
  const float* fc_W   = (const float*)d_in[20];
  const float* fc_b   = (const float*)d_in[21];

  char* base = (char*)d_ws;
  size_t off = 0;
  auto alloc_us = [&](size_t n){ u16* p = (u16*)(base + off); off += ((n * 2 + 15) & ~(size_t)15); return p; };
  auto alloc_f  = [&](size_t n){ float* p = (float*)(base + off); off += ((n * 4 + 15) & ~(size_t)15); return p; };

  u16 *We0ih_h = alloc_us((size_t)G4 * EPAD), *We0ih_l = alloc_us((size_t)G4 * EPAD);
  u16 *We0hh_h = alloc_us((size_t)G4 * HH),   *We0hh_l = alloc_us((size_t)G4 * HH);
  u16 *We1ih_h = alloc_us((size_t)G4 * HH),   *We1ih_l = alloc_us((size_t)G4 * HH);
  u16 *We1hh_h = alloc_us((size_t)G4 * HH),   *We1hh_l = alloc_us((size_t)G4 * HH);
  u16 *Wd0ih_h = alloc_us((size_t)G4 * EPAD), *Wd0ih_l = alloc_us((size_t)G4 * EPAD);
  u16 *Wd0hh_h = alloc_us((size_t)G4 * HH),   *Wd0hh_l = alloc_us((size_t)G4 * HH);
  u16 *Wd1ih_h = alloc_us((size_t)G4 * HH),   *Wd1ih_l = alloc_us((size_t)G4 * HH);
  u16 *Wd1hh_h = alloc_us((size_t)G4 * HH),   *Wd1hh_l = alloc_us((size_t)G4 * HH);
  u16 *Wfc_h   = alloc_us((size_t)NFC * HH),  *Wfc_l   = alloc_us((size_t)NFC * HH);
  u16 *Wc_h    = alloc_us((size_t)G4 * HH),   *Wc_l    = alloc_us((size_t)G4 * HH);
  float* be0 = alloc_f(G4);
  float* be1 = alloc_f(G4);
  float* bd0 = alloc_f(G4);
  float* bd1 = alloc_f(G4);
  float* bfc = alloc_f(NFC);
  float* bd0c = alloc_f(G4);
  float* Gp0 = alloc_f((size_t)BB * G4);
  float* Gp1 = alloc_f((size_t)BB * G4);
  // zero-init region: h0[0], h1[0] (hi+lo) then c0, c1 — one memset covers all
  u16* h0h[2]; u16* h0l[2]; u16* h1h[2]; u16* h1l[2];
  h0h[0] = alloc_us((size_t)BB * HH); h0l[0] = alloc_us((size_t)BB * HH);
  h1h[0] = alloc_us((size_t)BB * HH); h1l[0] = alloc_us((size_t)BB * HH);
  float* c0 = alloc_f((size_t)BB * HH);
  float* c1 = alloc_f((size_t)BB * HH);
  h0h[1] = alloc_us((size_t)BB * HH); h0l[1] = alloc_us((size_t)BB * HH);
  h1h[1] = alloc_us((size_t)BB * HH); h1l[1] = alloc_us((size_t)BB * HH);
  u16* inph = alloc_us((size_t)BB * EPAD);
  u16* inpl = alloc_us((size_t)BB * EPAD);
  u16* Xench = alloc_us((size_t)TT * BB * EPAD);
  u16* Xencl = alloc_us((size_t)TT * BB * EPAD);
  u16* histh = alloc_us((size_t)PP * BB * HH);
  u16* histl = alloc_us((size_t)PP * BB * HH);

  // prep: 3 fused launches + memset
  {
    SJobs js = {{
      { e_Wih0, We0ih_h, We0ih_l, G4, EE, G4, EPAD },
      { e_Whh0, We0hh_h, We0hh_l, G4, HH, G4, HH },
      { e_Wih1, We1ih_h, We1ih_l, G4, HH, G4, HH },
      { e_Whh1, We1hh_h, We1hh_l, G4, HH, G4, HH },
      { d_Wih0, Wd0ih_h, Wd0ih_l, G4, EE, G4, EPAD },
      { d_Whh0, Wd0hh_h, Wd0hh_l, G4, HH, G4, HH },
      { d_Wih1, Wd1ih_h, Wd1ih_l, G4, HH, G4, HH },
      { d_Whh1, Wd1hh_h, Wd1hh_l, G4, HH, G4, HH },
      { fc_W,   Wfc_h,   Wfc_l,   CC, HH, NFC, HH },
    }};
    split_multi<<<1024, 256, 0, stream>>>(js);
  }
  wcomb_fused<<<G4, 256, 0, stream>>>(d_Wih0, fc_W, d_bih0, d_bhh0, fc_b, Wc_h, Wc_l, bd0c);
  prep_misc<<<2048, 256, 0, stream>>>(
      e_bih0, e_bhh0, be0, e_bih1, e_bhh1, be1,
      d_bih0, d_bhh0, bd0, d_bih1, d_bhh1, bd1,
      fc_b, bfc, x_enc, inph, inpl, Xench, Xencl);
  hipMemsetAsync(h0h[0], 0, (size_t)4 * BB * HH * sizeof(u16) + (size_t)2 * BB * HH * sizeof(float), stream);

  // encoder: fused pipeline, iteration t runs cell0(t) and cell1(t-1); 512 blocks, M=64.
  // t==TT folds the decoder-prologue partial (Gp0 = h0_final @ Wd0hh) into the idle cell0 half.
  for (int t = 0; t <= TT; ++t){
    const int rd = t & 1, wrp = (t + 1) & 1;
    const size_t ts = (size_t)(t < TT ? t : 0) * BB * EPAD;
    lstm_pair<<<512, 256, SG_SMEM, stream>>>(
        (t < TT) ? 1 : 0, Xench + ts, Xencl + ts,
        We0ih_h, We0ih_l, We0hh_h, We0hh_l, be0,
        h0h[rd], h0l[rd], h0h[wrp], h0l[wrp], c0,
        (t > 0) ? 1 : 0, h0h[rd], h0l[rd],
        We1ih_h, We1ih_l, We1hh_h, We1hh_l, be1,
        h1h[wrp], h1l[wrp], h1h[rd], h1l[rd], c1,
        (t == TT) ? 1 : 0, Wd0hh_h, Wd0hh_l, Gp0);
  }
  // encoder finals land at parity 0 for both h0 and h1; Gp0 ready

  // decoder: split-overlap schedule (proven).
  // A(p)={fin0 (K=512/EPAD, +Gp0)} ∥ {part1: h1(p-1)@Wd1hh -> Gp1}
  // B(p)={fin1 (K=512, +Gp1), writes hist[p]} ∥ {part0: h0(p)@Wd0hh -> Gp0}
  const size_t S = (size_t)BB * HH;
  for (int p = 0; p < PP; ++p){
    const u16* hp_h = p ? histh + (size_t)(p - 1) * S : h1h[0];
    const u16* hp_l = p ? histl + (size_t)(p - 1) * S : h1l[0];
    dec_ab<<<512, 256, SG_SMEM, stream>>>(
        p ? hp_h : inph, p ? hp_l : inpl, p ? HH : EPAD,
        p ? Wc_h : Wd0ih_h, p ? Wc_l : Wd0ih_l,
        p ? bd0c : bd0, Gp0,
        h0h[1], h0l[1], c0,
        hp_h, hp_l, Wd1hh_h, Wd1hh_l, Gp1);
    dec_ab<<<512, 256, SG_SMEM, stream>>>(
        h0h[1], h0l[1], HH,
        Wd1ih_h, Wd1ih_l,
        bd1, Gp1,
        histh + (size_t)p * S, histl + (size_t)p * S, c1,
        h0h[1], h0l[1], Wd0hh_h, Wd0hh_l, Gp0);
  }

  // batched FC over all 96 decoder steps
  fc_batch<<<dim3((PP * BB) / 128, NFC / 64), 256, FC_SMEM, stream>>>(
      histh, histl, Wfc_h, Wfc_l, bfc, (float*)d_out);
}

// Round 11
// 5759.453 us; speedup vs baseline: 2.0604x; 2.0604x over previous
//
#include <hip/hip_runtime.h>
#include <hip/hip_bf16.h>

#define BB 512     // batch
#define TT 96      // encoder steps
#define PP 96      // decoder steps
#define EE 321     // input features
#define CC 321     // output channels
#define HH 512     // hidden
#define G4 2048    // 4*H
#define EPAD 352   // 321 padded to 32
#define NFC 384    // fc N pad (64-multiple)

// fc_batch (2-deep) staging
#define BUF_SZ 24576
#define XH_OFF 0
#define XL_OFF 8192
#define WH_OFF 16384
#define WL_OFF 20480
#define FC_SMEM 49152

// lstm M=64: 4-deep pipeline, 4 x (2*4096 + 8192) = 64KB -> 2 blocks/CU
#define LSTM_SMEM 65536

typedef unsigned short u16;
typedef __attribute__((ext_vector_type(8))) short bf16x8;
typedef __attribute__((ext_vector_type(16))) float floatx16;

__device__ __forceinline__ void splitf(float v, u16& h, u16& l){
  __hip_bfloat16 bh = __float2bfloat16(v);
  h = *reinterpret_cast<u16*>(&bh);
  float r = v - __bfloat162float(bh);
  __hip_bfloat16 bl = __float2bfloat16(r);
  l = *reinterpret_cast<u16*>(&bl);
}

// async global->LDS, 16B per lane; LDS dest = wave-uniform base + lane*16 (linear).
__device__ __forceinline__ void gload16(const void* g, void* l){
  __builtin_amdgcn_global_load_lds((const __attribute__((address_space(1))) void*)g,
                                   (__attribute__((address_space(3))) void*)l, 16, 0, 0);
}

// ---------- fused prep ----------
struct SJob { const float* src; u16* hi; u16* lo; int rows, cols, rowspad, colspad; };
struct SJobs { SJob j[9]; };

__global__ void split_multi(SJobs js){
  const int stride = gridDim.x * blockDim.x;
  const int t0 = blockIdx.x * blockDim.x + threadIdx.x;
  for (int k = 0; k < 9; ++k){
    const SJob J = js.j[k];
    const int total = J.rowspad * J.colspad;
    for (int idx = t0; idx < total; idx += stride){
      int r = idx / J.colspad, cc = idx - r * J.colspad;
      float v = (r < J.rows && cc < J.cols) ? J.src[(size_t)r * J.cols + cc] : 0.f;
      u16 h, l; splitf(v, h, l);
      J.hi[idx] = h; J.lo[idx] = l;
    }
  }
}

// Wcomb = Wd0ih @ fcW, split to bf16 hi/lo directly; bd0c = (d_bih0+d_bhh0) + Wd0ih @ fcb
__global__ void wcomb_fused(const float* __restrict__ A,
                            const float* __restrict__ Bm,
                            const float* __restrict__ bih, const float* __restrict__ bhh,
                            const float* __restrict__ fcb,
                            u16* __restrict__ Wc_h, u16* __restrict__ Wc_l,
                            float* __restrict__ bd0c){
  __shared__ float arow[EE];
  __shared__ float red[256];
  const int g = blockIdx.x;
  for (int e = threadIdx.x; e < EE; e += 256) arow[e] = A[(size_t)g * EE + e];
  __syncthreads();
  float ps = 0.f;
  for (int e = threadIdx.x; e < EE; e += 256) ps += arow[e] * fcb[e];
  red[threadIdx.x] = ps; __syncthreads();
  for (int s = 128; s > 0; s >>= 1){
    if (threadIdx.x < s) red[threadIdx.x] += red[threadIdx.x + s];
    __syncthreads();
  }
  if (threadIdx.x == 0) bd0c[g] = bih[g] + bhh[g] + red[0];
  for (int k = threadIdx.x; k < HH; k += 256){
    float s = 0.f;
    for (int e = 0; e < EE; ++e) s += arow[e] * Bm[(size_t)e * HH + k];
    u16 h, l; splitf(s, h, l);
    Wc_h[(size_t)g * HH + k] = h; Wc_l[(size_t)g * HH + k] = l;
  }
}

__global__ void prep_misc(
    const float* e_bih0, const float* e_bhh0, float* be0,
    const float* e_bih1, const float* e_bhh1, float* be1,
    const float* d_bih0, const float* d_bhh0, float* bd0,
    const float* d_bih1, const float* d_bhh1, float* bd1,
    const float* fc_b, float* bfc,
    const float* x_enc, u16* inph, u16* inpl, u16* xh, u16* xl){
  const int stride = gridDim.x * blockDim.x;
  const int t0 = blockIdx.x * blockDim.x + threadIdx.x;
  for (int i = t0; i < G4; i += stride){
    be0[i] = e_bih0[i] + e_bhh0[i];
    be1[i] = e_bih1[i] + e_bhh1[i];
    bd0[i] = d_bih0[i] + d_bhh0[i];
    bd1[i] = d_bih1[i] + d_bhh1[i];
  }
  for (int i = t0; i < NFC; i += stride) bfc[i] = (i < CC) ? fc_b[i] : 0.f;
  for (int idx = t0; idx < BB * EPAD; idx += stride){
    int b = idx / EPAD, j = idx - b * EPAD;
    float v = (j < EE) ? x_enc[(size_t)b * TT * EE + (size_t)(TT - 1) * EE + j] : 0.f;
    u16 h, l; splitf(v, h, l);
    inph[idx] = h; inpl[idx] = l;
  }
  for (int idx = t0; idx < TT * BB * EPAD; idx += stride){
    int e = idx % EPAD;
    int rest = idx / EPAD;
    int b = rest % BB;
    int t = rest / BB;
    float v = (e < EE) ? x_enc[((size_t)b * TT + t) * EE + e] : 0.f;
    u16 h, l; splitf(v, h, l);
    xh[idx] = h; xl[idx] = l;
  }
}

// ---------- LSTM cell body (round-7 proven: 4-buffer, depth-3, one barrier/chunk) ----------
// MT batch-rows x N=64 gate-cols. 4 waves. gload_lds pipeline, counted vmcnt.
// Hph==null => single-phase K. Gin!=null => add precomputed partial gates.
template<int MT>
__device__ __forceinline__ void lstm_body(
    char* smem, int bx,
    const u16* __restrict__ Xh, const u16* __restrict__ Xl, int K1pad,
    const u16* __restrict__ Wih_h, const u16* __restrict__ Wih_l,
    const u16* __restrict__ Whh_h, const u16* __restrict__ Whh_l,
    const float* __restrict__ bias, const float* __restrict__ Gin,
    const u16* __restrict__ Hph, const u16* __restrict__ Hpl,
    u16* __restrict__ Hnh, u16* __restrict__ Hnl,
    float* __restrict__ cst)
{
  constexpr int XROWB = MT * 64;
  constexpr int BUFB  = 2 * XROWB + 8192;
  constexpr int WH_O  = 2 * XROWB;
  constexpr int WL_O  = 2 * XROWB + 4096;

  float (*sG)[68] = (float (*)[68])(smem);   // aliases staging; used only after final syncthreads

  const int tid  = threadIdx.x;
  const int lane = tid & 63;
  const int wid  = tid >> 6;
  const int wm = wid >> 1, wn = wid & 1;
  const int m0 = (bx >> 5) * MT;
  const int u0 = (bx & 31) * 16;

  floatx16 acc0 = {0.f,0.f,0.f,0.f,0.f,0.f,0.f,0.f,0.f,0.f,0.f,0.f,0.f,0.f,0.f,0.f};
  floatx16 acc1 = acc0;   // dead (DCE'd) when MT==64

  const int ml    = lane & 31;
  const int thalf = lane >> 5;
  const int a0r = (MT == 128 ? wm * 64 : wm * 32) + ml;
  const int a1r = a0r + 32;                // MT==128 only
  const int brw = wn * 32 + ml;
  const int xa  = (a0r >> 1) & 3;
  const int xb  = (brw >> 1) & 3;

  const int sl  = lane & 3;
  const int rq  = lane >> 2;
  const int rx0 = wid * (MT / 4) + rq;
  const int rw  = wid * 16 + rq;
  const int sgx = (sl ^ ((rx0 >> 1) & 3)) << 4;
  const int sgw = (sl ^ ((rw  >> 1) & 3)) << 4;
  const size_t gxr0 = (size_t)(m0 + rx0);
  const size_t gxr1 = gxr0 + 16;                  // MT==128 only
  const size_t gwr  = (size_t)wid * HH + u0 + rq; // gate-row remap
  const int oX = wid * (MT / 4) * 64;
  const int oW = wid * 16 * 64;

  const int nch1 = K1pad >> 5;
  const int ncht = Hph ? nch1 + (HH >> 5) : nch1;  // >= 11 always

  auto stage = [&](int ch){
    const bool p1 = ch < nch1;
    const int k0 = (p1 ? ch : ch - nch1) << 5;
    const u16* xh = p1 ? Xh : Hph;
    const u16* xl = p1 ? Xl : Hpl;
    const u16* wh = p1 ? Wih_h : Whh_h;
    const u16* wl = p1 ? Wih_l : Whh_l;
    const size_t Kp = p1 ? (size_t)K1pad : (size_t)HH;
    char* b = smem + (ch & 3) * BUFB;
    gload16((const char*)(xh + gxr0 * Kp + k0) + sgx, b + oX);
    if constexpr (MT == 128) gload16((const char*)(xh + gxr1 * Kp + k0) + sgx, b + oX + 1024);
    gload16((const char*)(xl + gxr0 * Kp + k0) + sgx, b + XROWB + oX);
    if constexpr (MT == 128) gload16((const char*)(xl + gxr1 * Kp + k0) + sgx, b + XROWB + oX + 1024);
    gload16((const char*)(wh + gwr  * Kp + k0) + sgw, b + WH_O + oW);
    gload16((const char*)(wl + gwr  * Kp + k0) + sgw, b + WL_O + oW);
  };

  // prologue: 3 chunks in flight (ncht >= 11 always)
  stage(0); stage(1); stage(2);
  for (int ch = 0; ch < ncht; ++ch){
    const int rem = (ncht - 1 - ch) < 2 ? (ncht - 1 - ch) : 2;  // newer chunks in flight
    __builtin_amdgcn_sched_barrier(0);
    if constexpr (MT == 128){
      if      (rem == 2) asm volatile("s_waitcnt vmcnt(12)" ::: "memory");
      else if (rem == 1) asm volatile("s_waitcnt vmcnt(6)"  ::: "memory");
      else               asm volatile("s_waitcnt vmcnt(0)"  ::: "memory");
    } else {
      if      (rem == 2) asm volatile("s_waitcnt vmcnt(8)"  ::: "memory");
      else if (rem == 1) asm volatile("s_waitcnt vmcnt(4)"  ::: "memory");
      else               asm volatile("s_waitcnt vmcnt(0)"  ::: "memory");
    }
    asm volatile("s_waitcnt lgkmcnt(0)" ::: "memory");   // my ch-1 reads retired
    __builtin_amdgcn_s_barrier();                        // chunk ch resident; ch-1 reads globally done
    __builtin_amdgcn_sched_barrier(0);
    if (ch + 3 < ncht) stage(ch + 3);                    // writes buf (ch-1)&3: safe now
    const char* bufc = smem + (ch & 3) * BUFB;
    #pragma unroll
    for (int kk2 = 0; kk2 < 2; ++kk2){
      const int t0 = kk2 * 2 + thalf;
      bf16x8 ah0 = *(const bf16x8*)(bufc + a0r * 64 + ((t0 ^ xa) << 4));
      bf16x8 al0 = *(const bf16x8*)(bufc + XROWB + a0r * 64 + ((t0 ^ xa) << 4));
      bf16x8 bh  = *(const bf16x8*)(bufc + WH_O + brw * 64 + ((t0 ^ xb) << 4));
      bf16x8 bl  = *(const bf16x8*)(bufc + WL_O + brw * 64 + ((t0 ^ xb) << 4));
      acc0 = __builtin_amdgcn_mfma_f32_32x32x16_bf16(ah0, bh, acc0, 0, 0, 0);
      acc0 = __builtin_amdgcn_mfma_f32_32x32x16_bf16(ah0, bl, acc0, 0, 0, 0);
      acc0 = __builtin_amdgcn_mfma_f32_32x32x16_bf16(al0, bh, acc0, 0, 0, 0);
      if constexpr (MT == 128){
        bf16x8 ah1 = *(const bf16x8*)(bufc + a1r * 64 + ((t0 ^ xa) << 4));
        bf16x8 al1 = *(const bf16x8*)(bufc + XROWB + a1r * 64 + ((t0 ^ xa) << 4));
        acc1 = __builtin_amdgcn_mfma_f32_32x32x16_bf16(ah1, bh, acc1, 0, 0, 0);
        acc1 = __builtin_amdgcn_mfma_f32_32x32x16_bf16(ah1, bl, acc1, 0, 0, 0);
        acc1 = __builtin_amdgcn_mfma_f32_32x32x16_bf16(al1, bh, acc1, 0, 0, 0);
      }
    }
  }
  __syncthreads();  // drains lgkm/vm + barrier: safe to alias sG over staging buffers

  #pragma unroll
  for (int r = 0; r < 16; ++r){
    const int mm = (r & 3) + 8 * (r >> 2) + 4 * thalf;
    if constexpr (MT == 128){
      sG[wm * 64 + mm][wn * 32 + ml]      = acc0[r];
      sG[wm * 64 + 32 + mm][wn * 32 + ml] = acc1[r];
    } else {
      sG[wm * 32 + mm][wn * 32 + ml]      = acc0[r];
    }
  }
  __syncthreads();
  for (int e = tid; e < MT * 16; e += 256){
    const int m = e >> 4, u = e & 15;
    const int gj = u0 + u;
    float gi = sG[m][u]      + bias[gj];
    float gf = sG[m][16 + u] + bias[HH + gj];
    float gg = sG[m][32 + u] + bias[2 * HH + gj];
    float go = sG[m][48 + u] + bias[3 * HH + gj];
    if (Gin){
      const float* gb = Gin + (size_t)(m0 + m) * G4;
      gi += gb[gj]; gf += gb[HH + gj]; gg += gb[2 * HH + gj]; go += gb[3 * HH + gj];
    }
    const float si = 1.f / (1.f + expf(-gi));
    const float sf = 1.f / (1.f + expf(-gf));
    const float so = 1.f / (1.f + expf(-go));
    const size_t sidx = (size_t)(m0 + m) * HH + gj;
    const float cn = sf * cst[sidx] + si * tanhf(gg);
    const float hn = so * tanhf(cn);
    cst[sidx] = cn;
    u16 hh, hl; splitf(hn, hh, hl);
    Hnh[sidx] = hh; Hnl[sidx] = hl;
  }
}

// ---------- partial-gate GEMM: Gout[b][g*512+u] = X @ W^T (M=64 tile, K=512) ----------
__device__ __forceinline__ void part_body(
    char* smem, int bx,
    const u16* __restrict__ Xh, const u16* __restrict__ Xl,
    const u16* __restrict__ W_h, const u16* __restrict__ W_l,
    float* __restrict__ Gout)
{
  constexpr int XROWB = 64 * 64;
  constexpr int BUFB  = 2 * XROWB + 8192;
  constexpr int WH_O  = 2 * XROWB;
  constexpr int WL_O  = 2 * XROWB + 4096;

  const int tid  = threadIdx.x;
  const int lane = tid & 63;
  const int wid  = tid >> 6;
  const int wm = wid >> 1, wn = wid & 1;
  const int m0 = (bx >> 5) * 64;
  const int u0 = (bx & 31) * 16;

  floatx16 acc0 = {0.f,0.f,0.f,0.f,0.f,0.f,0.f,0.f,0.f,0.f,0.f,0.f,0.f,0.f,0.f,0.f};

  const int ml    = lane & 31;
  const int thalf = lane >> 5;
  const int a0r = wm * 32 + ml;
  const int brw = wn * 32 + ml;
  const int xa  = (a0r >> 1) & 3;
  const int xb  = (brw >> 1) & 3;

  const int sl  = lane & 3;
  const int rq  = lane >> 2;
  const int rx0 = wid * 16 + rq;
  const int rw  = wid * 16 + rq;
  const int sgx = (sl ^ ((rx0 >> 1) & 3)) << 4;
  const int sgw = (sl ^ ((rw  >> 1) & 3)) << 4;
  const size_t gxr0 = (size_t)(m0 + rx0);
  const size_t gwr  = (size_t)wid * HH + u0 + rq;
  const int oX = wid * 16 * 64;
  const int oW = wid * 16 * 64;

  auto stage = [&](int ch){
    const int k0 = ch << 5;
    char* b = smem + (ch & 3) * BUFB;
    gload16((const char*)(Xh + gxr0 * HH + k0) + sgx, b + oX);
    gload16((const char*)(Xl + gxr0 * HH + k0) + sgx, b + XROWB + oX);
    gload16((const char*)(W_h + gwr * HH + k0) + sgw, b + WH_O + oW);
    gload16((const char*)(W_l + gwr * HH + k0) + sgw, b + WL_O + oW);
  };

  stage(0); stage(1); stage(2);
  for (int ch = 0; ch < 16; ++ch){
    const int rem = (15 - ch) < 2 ? (15 - ch) : 2;
    __builtin_amdgcn_sched_barrier(0);
    if      (rem == 2) asm volatile("s_waitcnt vmcnt(8)" ::: "memory");
    else if (rem == 1) asm volatile("s_waitcnt vmcnt(4)" ::: "memory");
    else               asm volatile("s_waitcnt vmcnt(0)" ::: "memory");
    asm volatile("s_waitcnt lgkmcnt(0)" ::: "memory");
    __builtin_amdgcn_s_barrier();
    __builtin_amdgcn_sched_barrier(0);
    if (ch + 3 < 16) stage(ch + 3);
    const char* bufc = smem + (ch & 3) * BUFB;
    #pragma unroll
    for (int kk2 = 0; kk2 < 2; ++kk2){
      const int t0 = kk2 * 2 + thalf;
      bf16x8 ah0 = *(const bf16x8*)(bufc + a0r * 64 + ((t0 ^ xa) << 4));
      bf16x8 al0 = *(const bf16x8*)(bufc + XROWB + a0r * 64 + ((t0 ^ xa) << 4));
      bf16x8 bh  = *(const bf16x8*)(bufc + WH_O + brw * 64 + ((t0 ^ xb) << 4));
      bf16x8 bl  = *(const bf16x8*)(bufc + WL_O + brw * 64 + ((t0 ^ xb) << 4));
      acc0 = __builtin_amdgcn_mfma_f32_32x32x16_bf16(ah0, bh, acc0, 0, 0, 0);
      acc0 = __builtin_amdgcn_mfma_f32_32x32x16_bf16(ah0, bl, acc0, 0, 0, 0);
      acc0 = __builtin_amdgcn_mfma_f32_32x32x16_bf16(al0, bh, acc0, 0, 0, 0);
    }
  }
  // direct fp32 store: C col c -> gate (c>>4), unit u0+(c&15)
  const int c = wn * 32 + ml;
  const size_t gcolo = (size_t)(c >> 4) * HH + u0 + (c & 15);
  #pragma unroll
  for (int r = 0; r < 16; ++r){
    const int mm = (r & 3) + 8 * (r >> 2) + 4 * thalf;
    Gout[(size_t)(m0 + wm * 32 + mm) * G4 + gcolo] = acc0[r];
  }
}

// decoder combined launch: blocks [0,256) = cell-finish (K=512 or EPAD), [256,512) = partial GEMM
__global__ __launch_bounds__(256, 2) void dec_ab(
    const u16* Xfh, const u16* Xfl, int Kf,
    const u16* Wf_h, const u16* Wf_l,
    const float* bias, const float* Gin,
    u16* Hnh, u16* Hnl, float* cst,
    const u16* Xph, const u16* Xpl,
    const u16* Wp_h, const u16* Wp_l,
    float* Gout)
{
  extern __shared__ char smem[];
  if (blockIdx.x < 256)
    lstm_body<64>(smem, blockIdx.x, Xfh, Xfl, Kf, Wf_h, Wf_l, nullptr, nullptr,
                  bias, Gin, nullptr, nullptr, Hnh, Hnl, cst);
  else
    part_body(smem, blockIdx.x - 256, Xph, Xpl, Wp_h, Wp_l, Gout);
}

// Fused encoder step, M=64 tiles: blocks [0,256) = cell0(t), [256,512) = cell1(t-1).
// At t==TT (act0==0, do_part==1), the idle cell0 half runs the decoder-prologue partial:
// Gp0 = h0_final @ Wd0hh  (saves one serialized launch).
__global__ __launch_bounds__(256, 2) void lstm_pair(
    int act0, const u16* X0h, const u16* X0l,
    const u16* W0ih_h, const u16* W0ih_l, const u16* W0hh_h, const u16* W0hh_l,
    const float* b0, const u16* H0ph, const u16* H0pl, u16* H0nh, u16* H0nl, float* c0,
    int act1, const u16* X1h, const u16* X1l,
    const u16* W1ih_h, const u16* W1ih_l, const u16* W1hh_h, const u16* W1hh_l,
    const float* b1, const u16* H1ph, const u16* H1pl, u16* H1nh, u16* H1nl, float* c1,
    int do_part, const u16* Wp_h, const u16* Wp_l, float* Gout)
{
  extern __shared__ char smem[];
  const int half = blockIdx.x >> 8;
  const int bx   = blockIdx.x & 255;
  if (half == 0 && !act0){
    if (do_part) part_body(smem, bx, H0ph, H0pl, Wp_h, Wp_l, Gout);
    return;
  }
  if (half == 1 && !act1) return;
  lstm_body<64>(smem, bx,
                half ? X1h : X0h, half ? X1l : X0l, half ? HH : EPAD,
                half ? W1ih_h : W0ih_h, half ? W1ih_l : W0ih_l,
                half ? W1hh_h : W0hh_h, half ? W1hh_l : W0hh_l,
                half ? b1 : b0, nullptr,
                half ? H1ph : H0ph, half ? H1pl : H0pl,
                half ? H1nh : H0nh, half ? H1nl : H0nl,
                half ? c1 : c0);
}

// ---------- batched FC over all decoder steps (unchanged, proven) ----------
__global__ __launch_bounds__(256) void fc_batch(
    const u16* __restrict__ Hh, const u16* __restrict__ Hl,
    const u16* __restrict__ Wh, const u16* __restrict__ Wl,
    const float* __restrict__ bfc,
    float* __restrict__ out)
{
  extern __shared__ char smem[];
  const int tid = threadIdx.x, lane = tid & 63, wid = tid >> 6;
  const int wm = wid >> 1, wn = wid & 1;
  const int m0 = blockIdx.x * 128;      // row = p*512 + b
  const int n0 = blockIdx.y * 64;

  floatx16 acc0 = {0.f,0.f,0.f,0.f,0.f,0.f,0.f,0.f,0.f,0.f,0.f,0.f,0.f,0.f,0.f,0.f};
  floatx16 acc1 = {0.f,0.f,0.f,0.f,0.f,0.f,0.f,0.f,0.f,0.f,0.f,0.f,0.f,0.f,0.f,0.f};

  const int ml    = lane & 31;
  const int thalf = lane >> 5;
  const int a0r = wm * 64 + ml;
  const int a1r = a0r + 32;
  const int brw = wn * 32 + ml;
  const int xa  = (a0r >> 1) & 3;
  const int xb  = (brw >> 1) & 3;

  const int sl  = lane & 3;
  const int rq  = lane >> 2;
  const int rx0 = wid * 32 + rq;
  const int rw  = wid * 16 + rq;
  const int sgx = (sl ^ ((rx0 >> 1) & 3)) << 4;
  const int sgw = (sl ^ ((rw  >> 1) & 3)) << 4;
  const size_t gxr0 = (size_t)(m0 + rx0);
  const size_t gxr1 = gxr0 + 16;
  const size_t gwr  = (size_t)(n0 + rw);
  const int oX = wid * 32 * 64;
  const int oW = wid * 16 * 64;

  auto stage = [&](int ch){
    const int k0 = ch << 5;
    char* b = smem + (ch & 1) * BUF_SZ;
    gload16((const char*)(Hh + gxr0 * HH + k0) + sgx, b + XH_OFF + oX);
    gload16((const char*)(Hh + gxr1 * HH + k0) + sgx, b + XH_OFF + oX + 1024);
    gload16((const char*)(Hl + gxr0 * HH + k0) + sgx, b + XL_OFF + oX);
    gload16((const char*)(Hl + gxr1 * HH + k0) + sgx, b + XL_OFF + oX + 1024);
    gload16((const char*)(Wh + gwr  * HH + k0) + sgw, b + WH_OFF + oW);
    gload16((const char*)(Wl + gwr  * HH + k0) + sgw, b + WL_OFF + oW);
  };

  stage(0);
  for (int ch = 0; ch < 16; ++ch){
    if (ch + 1 < 16) stage(ch + 1);
    __builtin_amdgcn_sched_barrier(0);
    if (ch + 1 < 16) { asm volatile("s_waitcnt vmcnt(6)" ::: "memory"); }
    else             { asm volatile("s_waitcnt vmcnt(0)" ::: "memory"); }
    __builtin_amdgcn_s_barrier();
    __builtin_amdgcn_sched_barrier(0);
    const char* bufc = smem + (ch & 1) * BUF_SZ;
    #pragma unroll
    for (int kk2 = 0; kk2 < 2; ++kk2){
      const int t0 = kk2 * 2 + thalf;
      bf16x8 ah0 = *(const bf16x8*)(bufc + XH_OFF + a0r * 64 + ((t0 ^ xa) << 4));
      bf16x8 al0 = *(const bf16x8*)(bufc + XL_OFF + a0r * 64 + ((t0 ^ xa) << 4));
      bf16x8 ah1 = *(const bf16x8*)(bufc + XH_OFF + a1r * 64 + ((t0 ^ xa) << 4));
      bf16x8 al1 = *(const bf16x8*)(bufc + XL_OFF + a1r * 64 + ((t0 ^ xa) << 4));
      bf16x8 bh  = *(const bf16x8*)(bufc + WH_OFF + brw * 64 + ((t0 ^ xb) << 4));
      bf16x8 bl  = *(const bf16x8*)(bufc + WL_OFF + brw * 64 + ((t0 ^ xb) << 4));
      acc0 = __builtin_amdgcn_mfma_f32_32x32x16_bf16(ah0, bh, acc0, 0, 0, 0);
      acc0 = __builtin_amdgcn_mfma_f32_32x32x16_bf16(ah0, bl, acc0, 0, 0, 0);
      acc0 = __builtin_amdgcn_mfma_f32_32x32x16_bf16(al0, bh, acc0, 0, 0, 0);
      acc1 = __builtin_amdgcn_mfma_f32_32x32x16_bf16(ah1, bh, acc1, 0, 0, 0);
      acc1 = __builtin_amdgcn_mfma_f32_32x32x16_bf16(ah1, bl, acc1, 0, 0, 0);
      acc1 = __builtin_amdgcn_mfma_f32_32x32x16_bf16(al1, bh, acc1, 0, 0, 0);
    }
    __builtin_amdgcn_sched_barrier(0);
    asm volatile("s_waitcnt lgkmcnt(0)" ::: "memory");
    __builtin_amdgcn_s_barrier();
    __builtin_amdgcn_sched_barrier(0);
  }

  const int n = n0 + wn * 32 + ml;
  if (n < CC){
    const float bv = bfc[n];
    #pragma unroll
    for (int r = 0; r < 16; ++r){
      const int mm = (r & 3) + 8 * (r >> 2) + 4 * thalf;
      {
        const int rr = m0 + wm * 64 + mm;
        out[(size_t)(rr & 511) * PP * CC + (size_t)(rr >> 9) * CC + n] = acc0[r] + bv;
      }
      {
        const int rr = m0 + wm * 64 + 32 + mm;
        out[(size_t)(rr & 511) * PP * CC + (size_t)(rr >> 9) * CC + n] = acc1[r] + bv;
      }
    }
  }
}

extern "C" void kernel_launch(void* const* d_in, const int* in_sizes, int n_in,
                              void* d_out, int out_size, void* d_ws, size_t ws_size,
                              hipStream_t stream) {
  const float* x_enc  = (const float*)d_in[0];
  const float* e_Wih0 = (const float*)d_in[4];
  const float* e_Whh0 = (const float*)d_in[5];
  const float* e_bih0 = (const float*)d_in[6];
  const float* e_bhh0 = (const float*)d_in[7];
  const float* e_Wih1 = (const float*)d_in[8];
  const float* e_Whh1 = (const float*)d_in[9];
  const float* e_bih1 = (const float*)d_in[10];
  const float* e_bhh1 = (const float*)d_in[11];
  const float* d_Wih0 = (const float*)d_in[12];
  const float* d_Whh0 = (const float*)d_in[13];
  const float* d_bih0 = (const float*)d_in[14];
  const float* d_bhh0 = (const float*)d_in[15];
  const float* d_Wih1 = (const float*)d_in[16];
  const float* d_Whh1 = (const float*)d_in[17];
  const float* d_bih1 = (const float*)d_in[18];
  const float* d_bhh1 = (const float*)d_in[19];
  const float* fc_W   = (const float*)d_in[20];
  const float* fc_b   = (const float*)d_in[21];

  static bool attr_done = false;
  if (!attr_done){
    hipFuncSetAttribute((const void*)lstm_pair, hipFuncAttributeMaxDynamicSharedMemorySize, LSTM_SMEM);
    hipFuncSetAttribute((const void*)dec_ab,    hipFuncAttributeMaxDynamicSharedMemorySize, LSTM_SMEM);
    attr_done = true;
  }

  char* base = (char*)d_ws;
  size_t off = 0;
  auto alloc_us = [&](size_t n){ u16* p = (u16*)(base + off); off += ((n * 2 + 15) & ~(size_t)15); return p; };
  auto alloc_f  = [&](size_t n){ float* p = (float*)(base + off); off += ((n * 4 + 15) & ~(size_t)15); return p; };

  u16 *We0ih_h = alloc_us((size_t)G4 * EPAD), *We0ih_l = alloc_us((size_t)G4 * EPAD);
  u16 *We0hh_h = alloc_us((size_t)G4 * HH),   *We0hh_l = alloc_us((size_t)G4 * HH);
  u16 *We1ih_h = alloc_us((size_t)G4 * HH),   *We1ih_l = alloc_us((size_t)G4 * HH);
  u16 *We1hh_h = alloc_us((size_t)G4 * HH),   *We1hh_l = alloc_us((size_t)G4 * HH);
  u16 *Wd0ih_h = alloc_us((size_t)G4 * EPAD), *Wd0ih_l = alloc_us((size_t)G4 * EPAD);
  u16 *Wd0hh_h = alloc_us((size_t)G4 * HH),   *Wd0hh_l = alloc_us((size_t)G4 * HH);
  u16 *Wd1ih_h = alloc_us((size_t)G4 * HH),   *Wd1ih_l = alloc_us((size_t)G4 * HH);
  u16 *Wd1hh_h = alloc_us((size_t)G4 * HH),   *Wd1hh_l = alloc_us((size_t)G4 * HH);
  u16 *Wfc_h   = alloc_us((size_t)NFC * HH),  *Wfc_l   = alloc_us((size_t)NFC * HH);
  u16 *Wc_h    = alloc_us((size_t)G4 * HH),   *Wc_l    = alloc_us((size_t)G4 * HH);
  float* be0 = alloc_f(G4);
  float* be1 = alloc_f(G4);
  float* bd0 = alloc_f(G4);
  float* bd1 = alloc_f(G4);
  float* bfc = alloc_f(NFC);
  float* bd0c = alloc_f(G4);
  float* Gp0 = alloc_f((size_t)BB * G4);
  float* Gp1 = alloc_f((size_t)BB * G4);
  // zero-init region: h0[0], h1[0] (hi+lo) then c0, c1 — one memset covers all
  u16* h0h[2]; u16* h0l[2]; u16* h1h[2]; u16* h1l[2];
  h0h[0] = alloc_us((size_t)BB * HH); h0l[0] = alloc_us((size_t)BB * HH);
  h1h[0] = alloc_us((size_t)BB * HH); h1l[0] = alloc_us((size_t)BB * HH);
  float* c0 = alloc_f((size_t)BB * HH);
  float* c1 = alloc_f((size_t)BB * HH);
  h0h[1] = alloc_us((size_t)BB * HH); h0l[1] = alloc_us((size_t)BB * HH);
  h1h[1] = alloc_us((size_t)BB * HH); h1l[1] = alloc_us((size_t)BB * HH);
  u16* inph = alloc_us((size_t)BB * EPAD);
  u16* inpl = alloc_us((size_t)BB * EPAD);
  u16* Xench = alloc_us((size_t)TT * BB * EPAD);
  u16* Xencl = alloc_us((size_t)TT * BB * EPAD);
  u16* histh = alloc_us((size_t)PP * BB * HH);
  u16* histl = alloc_us((size_t)PP * BB * HH);

  // prep: 3 fused launches + memset
  {
    SJobs js = {{
      { e_Wih0, We0ih_h, We0ih_l, G4, EE, G4, EPAD },
      { e_Whh0, We0hh_h, We0hh_l, G4, HH, G4, HH },
      { e_Wih1, We1ih_h, We1ih_l, G4, HH, G4, HH },
      { e_Whh1, We1hh_h, We1hh_l, G4, HH, G4, HH },
      { d_Wih0, Wd0ih_h, Wd0ih_l, G4, EE, G4, EPAD },
      { d_Whh0, Wd0hh_h, Wd0hh_l, G4, HH, G4, HH },
      { d_Wih1, Wd1ih_h, Wd1ih_l, G4, HH, G4, HH },
      { d_Whh1, Wd1hh_h, Wd1hh_l, G4, HH, G4, HH },
      { fc_W,   Wfc_h,   Wfc_l,   CC, HH, NFC, HH },
    }};
    split_multi<<<1024, 256, 0, stream>>>(js);
  }
  wcomb_fused<<<G4, 256, 0, stream>>>(d_Wih0, fc_W, d_bih0, d_bhh0, fc_b, Wc_h, Wc_l, bd0c);
  prep_misc<<<2048, 256, 0, stream>>>(
      e_bih0, e_bhh0, be0, e_bih1, e_bhh1, be1,
      d_bih0, d_bhh0, bd0, d_bih1, d_bhh1, bd1,
      fc_b, bfc, x_enc, inph, inpl, Xench, Xencl);
  hipMemsetAsync(h0h[0], 0, (size_t)4 * BB * HH * sizeof(u16) + (size_t)2 * BB * HH * sizeof(float), stream);

  // encoder: fused pipeline, iteration t runs cell0(t) and cell1(t-1); M=64, 512 blocks, 2/CU.
  // t==TT folds the decoder-prologue partial (Gp0 = h0_final @ Wd0hh) into the idle cell0 half.
  for (int t = 0; t <= TT; ++t){
    const int rd = t & 1, wrp = (t + 1) & 1;
    const size_t ts = (size_t)(t < TT ? t : 0) * BB * EPAD;
    lstm_pair<<<512, 256, LSTM_SMEM, stream>>>(
        (t < TT) ? 1 : 0, Xench + ts, Xencl + ts,
        We0ih_h, We0ih_l, We0hh_h, We0hh_l, be0,
        h0h[rd], h0l[rd], h0h[wrp], h0l[wrp], c0,
        (t > 0) ? 1 : 0, h0h[rd], h0l[rd],
        We1ih_h, We1ih_l, We1hh_h, We1hh_l, be1,
        h1h[wrp], h1l[wrp], h1h[rd], h1l[rd], c1,
        (t == TT) ? 1 : 0, Wd0hh_h, Wd0hh_l, Gp0);
  }
  // encoder finals land at parity 0 for both h0 and h1; Gp0 ready

  // decoder: split-overlap schedule (round-5/7 proven).
  // A(p)={fin0 (K=512/EPAD, +Gp0)} ∥ {part1: h1(p-1)@Wd1hh -> Gp1}
  // B(p)={fin1 (K=512, +Gp1), writes hist[p]} ∥ {part0: h0(p)@Wd0hh -> Gp0}
  const size_t S = (size_t)BB * HH;
  for (int p = 0; p < PP; ++p){
    const u16* hp_h = p ? histh + (size_t)(p - 1) * S : h1h[0];
    const u16* hp_l = p ? histl + (size_t)(p - 1) * S : h1l[0];
    dec_ab<<<512, 256, LSTM_SMEM, stream>>>(
        p ? hp_h : inph, p ? hp_l : inpl, p ? HH : EPAD,
        p ? Wc_h : Wd0ih_h, p ? Wc_l : Wd0ih_l,
        p ? bd0c : bd0, Gp0,
        h0h[1], h0l[1], c0,
        hp_h, hp_l, Wd1hh_h, Wd1hh_l, Gp1);
    dec_ab<<<512, 256, LSTM_SMEM, stream>>>(
        h0h[1], h0l[1], HH,
        Wd1ih_h, Wd1ih_l,
        bd1, Gp1,
        histh + (size_t)p * S, histl + (size_t)p * S, c1,
        h0h[1], h0l[1], Wd0hh_h, Wd0hh_l, Gp0);
  }

  // batched FC over all 96 decoder steps
  fc_batch<<<dim3((PP * BB) / 128, NFC / 64), 256, FC_SMEM, stream>>>(
      histh, histl, Wfc_h, Wfc_l, bfc, (float*)d_out);
}

// Round 12
// 5751.634 us; speedup vs baseline: 2.0632x; 1.0014x over previous
//
#include <hip/hip_runtime.h>
#include <hip/hip_bf16.h>

#define BB 512     // batch
#define TT 96      // encoder steps
#define PP 96      // decoder steps
#define EE 321     // input features
#define CC 321     // output channels
#define HH 512     // hidden
#define G4 2048    // 4*H
#define EPAD 352   // 321 padded to 32
#define NFC 384    // fc N pad (64-multiple)

// fc_batch (2-deep) staging
#define BUF_SZ 24576
#define XH_OFF 0
#define XL_OFF 8192
#define WH_OFF 16384
#define WL_OFF 20480
#define FC_SMEM 49152

// lstm M=64: 4-deep pipeline, 4 x (2*4096 + 8192) = 64KB -> 2 blocks/CU
#define LSTM_SMEM 65536

typedef unsigned short u16;
typedef __attribute__((ext_vector_type(8))) short bf16x8;
typedef __attribute__((ext_vector_type(16))) float floatx16;
typedef __attribute__((ext_vector_type(4))) unsigned int uint4v;

__device__ __forceinline__ void splitf(float v, u16& h, u16& l){
  __hip_bfloat16 bh = __float2bfloat16(v);
  h = *reinterpret_cast<u16*>(&bh);
  float r = v - __bfloat162float(bh);
  __hip_bfloat16 bl = __float2bfloat16(r);
  l = *reinterpret_cast<u16*>(&bl);
}

// async global->LDS, 16B per lane; LDS dest = wave-uniform base + lane*16 (linear).
__device__ __forceinline__ void gload16(const void* g, void* l){
  __builtin_amdgcn_global_load_lds((const __attribute__((address_space(1))) void*)g,
                                   (__attribute__((address_space(3))) void*)l, 16, 0, 0);
}

// ---------- fused prep: ONE kernel, block-range partitioned (all jobs independent) ----------
// blocks [0,1024):      9 weight splits (grid-stride)
// blocks [1024,3072):   wcomb row g = bid-1024  (Wc = Wd0ih@fcW split; bd0c fold)
// blocks [3072,5120):   biases + inp split + x_enc re-layout (virtual grid 2048)
// blocks [5120,5632):   zero h0[0],h1[0],c0,c1 region (16B stores)
struct SJob { const float* src; u16* hi; u16* lo; int rows, cols, rowspad, colspad; };
struct SJobs { SJob j[9]; };

__global__ __launch_bounds__(256) void prep_all(
    SJobs js,
    const float* __restrict__ A,      // d_Wih0 [2048][321]
    const float* __restrict__ Bm,     // fc_W   [321][512]
    const float* dbih0, const float* dbhh0, const float* fcb,
    u16* __restrict__ Wc_h, u16* __restrict__ Wc_l, float* __restrict__ bd0c,
    const float* e_bih0, const float* e_bhh0, float* be0,
    const float* e_bih1, const float* e_bhh1, float* be1,
    float* bd0,
    const float* d_bih1, const float* d_bhh1, float* bd1,
    float* bfc,
    const float* x_enc, u16* inph, u16* inpl, u16* xh, u16* xl,
    unsigned* zbase, int zn16)        // zero region as 16B units
{
  __shared__ float arow[EE];
  __shared__ float red[256];
  const int bid = blockIdx.x;

  if (bid < 1024){
    // ----- weight splits -----
    const int stride = 1024 * 256;
    const int t0 = bid * 256 + threadIdx.x;
    for (int k = 0; k < 9; ++k){
      const SJob J = js.j[k];
      const int total = J.rowspad * J.colspad;
      for (int idx = t0; idx < total; idx += stride){
        int r = idx / J.colspad, cc = idx - r * J.colspad;
        float v = (r < J.rows && cc < J.cols) ? J.src[(size_t)r * J.cols + cc] : 0.f;
        u16 h, l; splitf(v, h, l);
        J.hi[idx] = h; J.lo[idx] = l;
      }
    }
  } else if (bid < 3072){
    // ----- wcomb + bias fold, row g -----
    const int g = bid - 1024;
    for (int e = threadIdx.x; e < EE; e += 256) arow[e] = A[(size_t)g * EE + e];
    __syncthreads();
    float ps = 0.f;
    for (int e = threadIdx.x; e < EE; e += 256) ps += arow[e] * fcb[e];
    red[threadIdx.x] = ps; __syncthreads();
    for (int s = 128; s > 0; s >>= 1){
      if (threadIdx.x < s) red[threadIdx.x] += red[threadIdx.x + s];
      __syncthreads();
    }
    if (threadIdx.x == 0) bd0c[g] = dbih0[g] + dbhh0[g] + red[0];
    for (int k = threadIdx.x; k < HH; k += 256){
      float s = 0.f;
      for (int e = 0; e < EE; ++e) s += arow[e] * Bm[(size_t)e * HH + k];
      u16 h, l; splitf(s, h, l);
      Wc_h[(size_t)g * HH + k] = h; Wc_l[(size_t)g * HH + k] = l;
    }
  } else if (bid < 5120){
    // ----- biases + inp + x_enc relayout (virtual grid of 2048 blocks) -----
    const int vb = bid - 3072;
    const int stride = 2048 * 256;
    const int t0 = vb * 256 + threadIdx.x;
    for (int i = t0; i < G4; i += stride){
      be0[i] = e_bih0[i] + e_bhh0[i];
      be1[i] = e_bih1[i] + e_bhh1[i];
      bd0[i] = dbih0[i] + dbhh0[i];
      bd1[i] = d_bih1[i] + d_bhh1[i];
    }
    for (int i = t0; i < NFC; i += stride) bfc[i] = (i < CC) ? fcb[i] : 0.f;
    for (int idx = t0; idx < BB * EPAD; idx += stride){
      int b = idx / EPAD, j = idx - b * EPAD;
      float v = (j < EE) ? x_enc[(size_t)b * TT * EE + (size_t)(TT - 1) * EE + j] : 0.f;
      u16 h, l; splitf(v, h, l);
      inph[idx] = h; inpl[idx] = l;
    }
    for (int idx = t0; idx < TT * BB * EPAD; idx += stride){
      int e = idx % EPAD;
      int rest = idx / EPAD;
      int b = rest % BB;
      int t = rest / BB;
      float v = (e < EE) ? x_enc[((size_t)b * TT + t) * EE + e] : 0.f;
      u16 h, l; splitf(v, h, l);
      xh[idx] = h; xl[idx] = l;
    }
  } else {
    // ----- zero state region -----
    const int vb = bid - 5120;
    uint4v z = {0u, 0u, 0u, 0u};
    const int stride = 512 * 256;
    for (int i = vb * 256 + threadIdx.x; i < zn16; i += stride)
      *reinterpret_cast<uint4v*>(zbase + (size_t)i * 4) = z;
  }
}

// ---------- LSTM cell body (round-7 proven: 4-buffer, depth-3, one barrier/chunk) ----------
// MT batch-rows x N=64 gate-cols. 4 waves. gload_lds pipeline, counted vmcnt.
// Hph==null => single-phase K. Gin!=null => add precomputed partial gates.
template<int MT>
__device__ __forceinline__ void lstm_body(
    char* smem, int bx,
    const u16* __restrict__ Xh, const u16* __restrict__ Xl, int K1pad,
    const u16* __restrict__ Wih_h, const u16* __restrict__ Wih_l,
    const u16* __restrict__ Whh_h, const u16* __restrict__ Whh_l,
    const float* __restrict__ bias, const float* __restrict__ Gin,
    const u16* __restrict__ Hph, const u16* __restrict__ Hpl,
    u16* __restrict__ Hnh, u16* __restrict__ Hnl,
    float* __restrict__ cst)
{
  constexpr int XROWB = MT * 64;
  constexpr int BUFB  = 2 * XROWB + 8192;
  constexpr int WH_O  = 2 * XROWB;
  constexpr int WL_O  = 2 * XROWB + 4096;

  float (*sG)[68] = (float (*)[68])(smem);   // aliases staging; used only after final syncthreads

  const int tid  = threadIdx.x;
  const int lane = tid & 63;
  const int wid  = tid >> 6;
  const int wm = wid >> 1, wn = wid & 1;
  const int m0 = (bx >> 5) * MT;
  const int u0 = (bx & 31) * 16;

  floatx16 acc0 = {0.f,0.f,0.f,0.f,0.f,0.f,0.f,0.f,0.f,0.f,0.f,0.f,0.f,0.f,0.f,0.f};
  floatx16 acc1 = acc0;   // dead (DCE'd) when MT==64

  const int ml    = lane & 31;
  const int thalf = lane >> 5;
  const int a0r = (MT == 128 ? wm * 64 : wm * 32) + ml;
  const int a1r = a0r + 32;                // MT==128 only
  const int brw = wn * 32 + ml;
  const int xa  = (a0r >> 1) & 3;
  const int xb  = (brw >> 1) & 3;

  const int sl  = lane & 3;
  const int rq  = lane >> 2;
  const int rx0 = wid * (MT / 4) + rq;
  const int rw  = wid * 16 + rq;
  const int sgx = (sl ^ ((rx0 >> 1) & 3)) << 4;
  const int sgw = (sl ^ ((rw  >> 1) & 3)) << 4;
  const size_t gxr0 = (size_t)(m0 + rx0);
  const size_t gxr1 = gxr0 + 16;                  // MT==128 only
  const size_t gwr  = (size_t)wid * HH + u0 + rq; // gate-row remap
  const int oX = wid * (MT / 4) * 64;
  const int oW = wid * 16 * 64;

  const int nch1 = K1pad >> 5;
  const int ncht = Hph ? nch1 + (HH >> 5) : nch1;  // >= 11 always

  auto stage = [&](int ch){
    const bool p1 = ch < nch1;
    const int k0 = (p1 ? ch : ch - nch1) << 5;
    const u16* xh = p1 ? Xh : Hph;
    const u16* xl = p1 ? Xl : Hpl;
    const u16* wh = p1 ? Wih_h : Whh_h;
    const u16* wl = p1 ? Wih_l : Whh_l;
    const size_t Kp = p1 ? (size_t)K1pad : (size_t)HH;
    char* b = smem + (ch & 3) * BUFB;
    gload16((const char*)(xh + gxr0 * Kp + k0) + sgx, b + oX);
    if constexpr (MT == 128) gload16((const char*)(xh + gxr1 * Kp + k0) + sgx, b + oX + 1024);
    gload16((const char*)(xl + gxr0 * Kp + k0) + sgx, b + XROWB + oX);
    if constexpr (MT == 128) gload16((const char*)(xl + gxr1 * Kp + k0) + sgx, b + XROWB + oX + 1024);
    gload16((const char*)(wh + gwr  * Kp + k0) + sgw, b + WH_O + oW);
    gload16((const char*)(wl + gwr  * Kp + k0) + sgw, b + WL_O + oW);
  };

  // prologue: 3 chunks in flight (ncht >= 11 always)
  stage(0); stage(1); stage(2);
  for (int ch = 0; ch < ncht; ++ch){
    const int rem = (ncht - 1 - ch) < 2 ? (ncht - 1 - ch) : 2;  // newer chunks in flight
    __builtin_amdgcn_sched_barrier(0);
    if constexpr (MT == 128){
      if      (rem == 2) asm volatile("s_waitcnt vmcnt(12)" ::: "memory");
      else if (rem == 1) asm volatile("s_waitcnt vmcnt(6)"  ::: "memory");
      else               asm volatile("s_waitcnt vmcnt(0)"  ::: "memory");
    } else {
      if      (rem == 2) asm volatile("s_waitcnt vmcnt(8)"  ::: "memory");
      else if (rem == 1) asm volatile("s_waitcnt vmcnt(4)"  ::: "memory");
      else               asm volatile("s_waitcnt vmcnt(0)"  ::: "memory");
    }
    asm volatile("s_waitcnt lgkmcnt(0)" ::: "memory");   // my ch-1 reads retired
    __builtin_amdgcn_s_barrier();                        // chunk ch resident; ch-1 reads globally done
    __builtin_amdgcn_sched_barrier(0);
    if (ch + 3 < ncht) stage(ch + 3);                    // writes buf (ch-1)&3: safe now
    const char* bufc = smem + (ch & 3) * BUFB;
    #pragma unroll
    for (int kk2 = 0; kk2 < 2; ++kk2){
      const int t0 = kk2 * 2 + thalf;
      bf16x8 ah0 = *(const bf16x8*)(bufc + a0r * 64 + ((t0 ^ xa) << 4));
      bf16x8 al0 = *(const bf16x8*)(bufc + XROWB + a0r * 64 + ((t0 ^ xa) << 4));
      bf16x8 bh  = *(const bf16x8*)(bufc + WH_O + brw * 64 + ((t0 ^ xb) << 4));
      bf16x8 bl  = *(const bf16x8*)(bufc + WL_O + brw * 64 + ((t0 ^ xb) << 4));
      acc0 = __builtin_amdgcn_mfma_f32_32x32x16_bf16(ah0, bh, acc0, 0, 0, 0);
      acc0 = __builtin_amdgcn_mfma_f32_32x32x16_bf16(ah0, bl, acc0, 0, 0, 0);
      acc0 = __builtin_amdgcn_mfma_f32_32x32x16_bf16(al0, bh, acc0, 0, 0, 0);
      if constexpr (MT == 128){
        bf16x8 ah1 = *(const bf16x8*)(bufc + a1r * 64 + ((t0 ^ xa) << 4));
        bf16x8 al1 = *(const bf16x8*)(bufc + XROWB + a1r * 64 + ((t0 ^ xa) << 4));
        acc1 = __builtin_amdgcn_mfma_f32_32x32x16_bf16(ah1, bh, acc1, 0, 0, 0);
        acc1 = __builtin_amdgcn_mfma_f32_32x32x16_bf16(ah1, bl, acc1, 0, 0, 0);
        acc1 = __builtin_amdgcn_mfma_f32_32x32x16_bf16(al1, bh, acc1, 0, 0, 0);
      }
    }
  }
  __syncthreads();  // drains lgkm/vm + barrier: safe to alias sG over staging buffers

  #pragma unroll
  for (int r = 0; r < 16; ++r){
    const int mm = (r & 3) + 8 * (r >> 2) + 4 * thalf;
    if constexpr (MT == 128){
      sG[wm * 64 + mm][wn * 32 + ml]      = acc0[r];
      sG[wm * 64 + 32 + mm][wn * 32 + ml] = acc1[r];
    } else {
      sG[wm * 32 + mm][wn * 32 + ml]      = acc0[r];
    }
  }
  __syncthreads();
  for (int e = tid; e < MT * 16; e += 256){
    const int m = e >> 4, u = e & 15;
    const int gj = u0 + u;
    float gi = sG[m][u]      + bias[gj];
    float gf = sG[m][16 + u] + bias[HH + gj];
    float gg = sG[m][32 + u] + bias[2 * HH + gj];
    float go = sG[m][48 + u] + bias[3 * HH + gj];
    if (Gin){
      const float* gb = Gin + (size_t)(m0 + m) * G4;
      gi += gb[gj]; gf += gb[HH + gj]; gg += gb[2 * HH + gj]; go += gb[3 * HH + gj];
    }
    const float si = 1.f / (1.f + expf(-gi));
    const float sf = 1.f / (1.f + expf(-gf));
    const float so = 1.f / (1.f + expf(-go));
    const size_t sidx = (size_t)(m0 + m) * HH + gj;
    const float cn = sf * cst[sidx] + si * tanhf(gg);
    const float hn = so * tanhf(cn);
    cst[sidx] = cn;
    u16 hh, hl; splitf(hn, hh, hl);
    Hnh[sidx] = hh; Hnl[sidx] = hl;
  }
}

// ---------- partial-gate GEMM: Gout[b][g*512+u] = X @ W^T (M=64 tile, K=512) ----------
__device__ __forceinline__ void part_body(
    char* smem, int bx,
    const u16* __restrict__ Xh, const u16* __restrict__ Xl,
    const u16* __restrict__ W_h, const u16* __restrict__ W_l,
    float* __restrict__ Gout)
{
  constexpr int XROWB = 64 * 64;
  constexpr int BUFB  = 2 * XROWB + 8192;
  constexpr int WH_O  = 2 * XROWB;
  constexpr int WL_O  = 2 * XROWB + 4096;

  const int tid  = threadIdx.x;
  const int lane = tid & 63;
  const int wid  = tid >> 6;
  const int wm = wid >> 1, wn = wid & 1;
  const int m0 = (bx >> 5) * 64;
  const int u0 = (bx & 31) * 16;

  floatx16 acc0 = {0.f,0.f,0.f,0.f,0.f,0.f,0.f,0.f,0.f,0.f,0.f,0.f,0.f,0.f,0.f,0.f};

  const int ml    = lane & 31;
  const int thalf = lane >> 5;
  const int a0r = wm * 32 + ml;
  const int brw = wn * 32 + ml;
  const int xa  = (a0r >> 1) & 3;
  const int xb  = (brw >> 1) & 3;

  const int sl  = lane & 3;
  const int rq  = lane >> 2;
  const int rx0 = wid * 16 + rq;
  const int rw  = wid * 16 + rq;
  const int sgx = (sl ^ ((rx0 >> 1) & 3)) << 4;
  const int sgw = (sl ^ ((rw  >> 1) & 3)) << 4;
  const size_t gxr0 = (size_t)(m0 + rx0);
  const size_t gwr  = (size_t)wid * HH + u0 + rq;
  const int oX = wid * 16 * 64;
  const int oW = wid * 16 * 64;

  auto stage = [&](int ch){
    const int k0 = ch << 5;
    char* b = smem + (ch & 3) * BUFB;
    gload16((const char*)(Xh + gxr0 * HH + k0) + sgx, b + oX);
    gload16((const char*)(Xl + gxr0 * HH + k0) + sgx, b + XROWB + oX);
    gload16((const char*)(W_h + gwr * HH + k0) + sgw, b + WH_O + oW);
    gload16((const char*)(W_l + gwr * HH + k0) + sgw, b + WL_O + oW);
  };

  stage(0); stage(1); stage(2);
  for (int ch = 0; ch < 16; ++ch){
    const int rem = (15 - ch) < 2 ? (15 - ch) : 2;
    __builtin_amdgcn_sched_barrier(0);
    if      (rem == 2) asm volatile("s_waitcnt vmcnt(8)" ::: "memory");
    else if (rem == 1) asm volatile("s_waitcnt vmcnt(4)" ::: "memory");
    else               asm volatile("s_waitcnt vmcnt(0)" ::: "memory");
    asm volatile("s_waitcnt lgkmcnt(0)" ::: "memory");
    __builtin_amdgcn_s_barrier();
    __builtin_amdgcn_sched_barrier(0);
    if (ch + 3 < 16) stage(ch + 3);
    const char* bufc = smem + (ch & 3) * BUFB;
    #pragma unroll
    for (int kk2 = 0; kk2 < 2; ++kk2){
      const int t0 = kk2 * 2 + thalf;
      bf16x8 ah0 = *(const bf16x8*)(bufc + a0r * 64 + ((t0 ^ xa) << 4));
      bf16x8 al0 = *(const bf16x8*)(bufc + XROWB + a0r * 64 + ((t0 ^ xa) << 4));
      bf16x8 bh  = *(const bf16x8*)(bufc + WH_O + brw * 64 + ((t0 ^ xb) << 4));
      bf16x8 bl  = *(const bf16x8*)(bufc + WL_O + brw * 64 + ((t0 ^ xb) << 4));
      acc0 = __builtin_amdgcn_mfma_f32_32x32x16_bf16(ah0, bh, acc0, 0, 0, 0);
      acc0 = __builtin_amdgcn_mfma_f32_32x32x16_bf16(ah0, bl, acc0, 0, 0, 0);
      acc0 = __builtin_amdgcn_mfma_f32_32x32x16_bf16(al0, bh, acc0, 0, 0, 0);
    }
  }
  // direct fp32 store: C col c -> gate (c>>4), unit u0+(c&15)
  const int c = wn * 32 + ml;
  const size_t gcolo = (size_t)(c >> 4) * HH + u0 + (c & 15);
  #pragma unroll
  for (int r = 0; r < 16; ++r){
    const int mm = (r & 3) + 8 * (r >> 2) + 4 * thalf;
    Gout[(size_t)(m0 + wm * 32 + mm) * G4 + gcolo] = acc0[r];
  }
}

// decoder combined launch: blocks [0,256) = cell-finish (K=512 or EPAD), [256,512) = partial GEMM
__global__ __launch_bounds__(256, 2) void dec_ab(
    const u16* Xfh, const u16* Xfl, int Kf,
    const u16* Wf_h, const u16* Wf_l,
    const float* bias, const float* Gin,
    u16* Hnh, u16* Hnl, float* cst,
    const u16* Xph, const u16* Xpl,
    const u16* Wp_h, const u16* Wp_l,
    float* Gout)
{
  extern __shared__ char smem[];
  if (blockIdx.x < 256)
    lstm_body<64>(smem, blockIdx.x, Xfh, Xfl, Kf, Wf_h, Wf_l, nullptr, nullptr,
                  bias, Gin, nullptr, nullptr, Hnh, Hnl, cst);
  else
    part_body(smem, blockIdx.x - 256, Xph, Xpl, Wp_h, Wp_l, Gout);
}

// Fused encoder step, M=64 tiles: blocks [0,256) = cell0(t), [256,512) = cell1(t-1).
// At t==TT (act0==0, do_part==1), the idle cell0 half runs the decoder-prologue partial:
// Gp0 = h0_final @ Wd0hh  (saves one serialized launch).
__global__ __launch_bounds__(256, 2) void lstm_pair(
    int act0, const u16* X0h, const u16* X0l,
    const u16* W0ih_h, const u16* W0ih_l, const u16* W0hh_h, const u16* W0hh_l,
    const float* b0, const u16* H0ph, const u16* H0pl, u16* H0nh, u16* H0nl, float* c0,
    int act1, const u16* X1h, const u16* X1l,
    const u16* W1ih_h, const u16* W1ih_l, const u16* W1hh_h, const u16* W1hh_l,
    const float* b1, const u16* H1ph, const u16* H1pl, u16* H1nh, u16* H1nl, float* c1,
    int do_part, const u16* Wp_h, const u16* Wp_l, float* Gout)
{
  extern __shared__ char smem[];
  const int half = blockIdx.x >> 8;
  const int bx   = blockIdx.x & 255;
  if (half == 0 && !act0){
    if (do_part) part_body(smem, bx, H0ph, H0pl, Wp_h, Wp_l, Gout);
    return;
  }
  if (half == 1 && !act1) return;
  lstm_body<64>(smem, bx,
                half ? X1h : X0h, half ? X1l : X0l, half ? HH : EPAD,
                half ? W1ih_h : W0ih_h, half ? W1ih_l : W0ih_l,
                half ? W1hh_h : W0hh_h, half ? W1hh_l : W0hh_l,
                half ? b1 : b0, nullptr,
                half ? H1ph : H0ph, half ? H1pl : H0pl,
                half ? H1nh : H0nh, half ? H1nl : H0nl,
                half ? c1 : c0);
}

// ---------- batched FC over all decoder steps (unchanged, proven) ----------
__global__ __launch_bounds__(256) void fc_batch(
    const u16* __restrict__ Hh, const u16* __restrict__ Hl,
    const u16* __restrict__ Wh, const u16* __restrict__ Wl,
    const float* __restrict__ bfc,
    float* __restrict__ out)
{
  extern __shared__ char smem[];
  const int tid = threadIdx.x, lane = tid & 63, wid = tid >> 6;
  const int wm = wid >> 1, wn = wid & 1;
  const int m0 = blockIdx.x * 128;      // row = p*512 + b
  const int n0 = blockIdx.y * 64;

  floatx16 acc0 = {0.f,0.f,0.f,0.f,0.f,0.f,0.f,0.f,0.f,0.f,0.f,0.f,0.f,0.f,0.f,0.f};
  floatx16 acc1 = {0.f,0.f,0.f,0.f,0.f,0.f,0.f,0.f,0.f,0.f,0.f,0.f,0.f,0.f,0.f,0.f};

  const int ml    = lane & 31;
  const int thalf = lane >> 5;
  const int a0r = wm * 64 + ml;
  const int a1r = a0r + 32;
  const int brw = wn * 32 + ml;
  const int xa  = (a0r >> 1) & 3;
  const int xb  = (brw >> 1) & 3;

  const int sl  = lane & 3;
  const int rq  = lane >> 2;
  const int rx0 = wid * 32 + rq;
  const int rw  = wid * 16 + rq;
  const int sgx = (sl ^ ((rx0 >> 1) & 3)) << 4;
  const int sgw = (sl ^ ((rw  >> 1) & 3)) << 4;
  const size_t gxr0 = (size_t)(m0 + rx0);
  const size_t gxr1 = gxr0 + 16;
  const size_t gwr  = (size_t)(n0 + rw);
  const int oX = wid * 32 * 64;
  const int oW = wid * 16 * 64;

  auto stage = [&](int ch){
    const int k0 = ch << 5;
    char* b = smem + (ch & 1) * BUF_SZ;
    gload16((const char*)(Hh + gxr0 * HH + k0) + sgx, b + XH_OFF + oX);
    gload16((const char*)(Hh + gxr1 * HH + k0) + sgx, b + XH_OFF + oX + 1024);
    gload16((const char*)(Hl + gxr0 * HH + k0) + sgx, b + XL_OFF + oX);
    gload16((const char*)(Hl + gxr1 * HH + k0) + sgx, b + XL_OFF + oX + 1024);
    gload16((const char*)(Wh + gwr  * HH + k0) + sgw, b + WH_OFF + oW);
    gload16((const char*)(Wl + gwr  * HH + k0) + sgw, b + WL_OFF + oW);
  };

  stage(0);
  for (int ch = 0; ch < 16; ++ch){
    if (ch + 1 < 16) stage(ch + 1);
    __builtin_amdgcn_sched_barrier(0);
    if (ch + 1 < 16) { asm volatile("s_waitcnt vmcnt(6)" ::: "memory"); }
    else             { asm volatile("s_waitcnt vmcnt(0)" ::: "memory"); }
    __builtin_amdgcn_s_barrier();
    __builtin_amdgcn_sched_barrier(0);
    const char* bufc = smem + (ch & 1) * BUF_SZ;
    #pragma unroll
    for (int kk2 = 0; kk2 < 2; ++kk2){
      const int t0 = kk2 * 2 + thalf;
      bf16x8 ah0 = *(const bf16x8*)(bufc + XH_OFF + a0r * 64 + ((t0 ^ xa) << 4));
      bf16x8 al0 = *(const bf16x8*)(bufc + XL_OFF + a0r * 64 + ((t0 ^ xa) << 4));
      bf16x8 ah1 = *(const bf16x8*)(bufc + XH_OFF + a1r * 64 + ((t0 ^ xa) << 4));
      bf16x8 al1 = *(const bf16x8*)(bufc + XL_OFF + a1r * 64 + ((t0 ^ xa) << 4));
      bf16x8 bh  = *(const bf16x8*)(bufc + WH_OFF + brw * 64 + ((t0 ^ xb) << 4));
      bf16x8 bl  = *(const bf16x8*)(bufc + WL_OFF + brw * 64 + ((t0 ^ xb) << 4));
      acc0 = __builtin_amdgcn_mfma_f32_32x32x16_bf16(ah0, bh, acc0, 0, 0, 0);
      acc0 = __builtin_amdgcn_mfma_f32_32x32x16_bf16(ah0, bl, acc0, 0, 0, 0);
      acc0 = __builtin_amdgcn_mfma_f32_32x32x16_bf16(al0, bh, acc0, 0, 0, 0);
      acc1 = __builtin_amdgcn_mfma_f32_32x32x16_bf16(ah1, bh, acc1, 0, 0, 0);
      acc1 = __builtin_amdgcn_mfma_f32_32x32x16_bf16(ah1, bl, acc1, 0, 0, 0);
      acc1 = __builtin_amdgcn_mfma_f32_32x32x16_bf16(al1, bh, acc1, 0, 0, 0);
    }
    __builtin_amdgcn_sched_barrier(0);
    asm volatile("s_waitcnt lgkmcnt(0)" ::: "memory");
    __builtin_amdgcn_s_barrier();
    __builtin_amdgcn_sched_barrier(0);
  }

  const int n = n0 + wn * 32 + ml;
  if (n < CC){
    const float bv = bfc[n];
    #pragma unroll
    for (int r = 0; r < 16; ++r){
      const int mm = (r & 3) + 8 * (r >> 2) + 4 * thalf;
      {
        const int rr = m0 + wm * 64 + mm;
        out[(size_t)(rr & 511) * PP * CC + (size_t)(rr >> 9) * CC + n] = acc0[r] + bv;
      }
      {
        const int rr = m0 + wm * 64 + 32 + mm;
        out[(size_t)(rr & 511) * PP * CC + (size_t)(rr >> 9) * CC + n] = acc1[r] + bv;
      }
    }
  }
}

extern "C" void kernel_launch(void* const* d_in, const int* in_sizes, int n_in,
                              void* d_out, int out_size, void* d_ws, size_t ws_size,
                              hipStream_t stream) {
  const float* x_enc  = (const float*)d_in[0];
  const float* e_Wih0 = (const float*)d_in[4];
  const float* e_Whh0 = (const float*)d_in[5];
  const float* e_bih0 = (const float*)d_in[6];
  const float* e_bhh0 = (const float*)d_in[7];
  const float* e_Wih1 = (const float*)d_in[8];
  const float* e_Whh1 = (const float*)d_in[9];
  const float* e_bih1 = (const float*)d_in[10];
  const float* e_bhh1 = (const float*)d_in[11];
  const float* d_Wih0 = (const float*)d_in[12];
  const float* d_Whh0 = (const float*)d_in[13];
  const float* d_bih0 = (const float*)d_in[14];
  const float* d_bhh0 = (const float*)d_in[15];
  const float* d_Wih1 = (const float*)d_in[16];
  const float* d_Whh1 = (const float*)d_in[17];
  const float* d_bih1 = (const float*)d_in[18];
  const float* d_bhh1 = (const float*)d_in[19];
  const float* fc_W   = (const float*)d_in[20];
  const float* fc_b   = (const float*)d_in[21];

  static bool attr_done = false;
  if (!attr_done){
    hipFuncSetAttribute((const void*)lstm_pair, hipFuncAttributeMaxDynamicSharedMemorySize, LSTM_SMEM);
    hipFuncSetAttribute((const void*)dec_ab,    hipFuncAttributeMaxDynamicSharedMemorySize, LSTM_SMEM);
    attr_done = true;
  }

  char* base = (char*)d_ws;
  size_t off = 0;
  auto alloc_us = [&](size_t n){ u16* p = (u16*)(base + off); off += ((n * 2 + 15) & ~(size_t)15); return p; };
  auto alloc_f  = [&](size_t n){ float* p = (float*)(base + off); off += ((n * 4 + 15) & ~(size_t)15); return p; };

  u16 *We0ih_h = alloc_us((size_t)G4 * EPAD), *We0ih_l = alloc_us((size_t)G4 * EPAD);
  u16 *We0hh_h = alloc_us((size_t)G4 * HH),   *We0hh_l = alloc_us((size_t)G4 * HH);
  u16 *We1ih_h = alloc_us((size_t)G4 * HH),   *We1ih_l = alloc_us((size_t)G4 * HH);
  u16 *We1hh_h = alloc_us((size_t)G4 * HH),   *We1hh_l = alloc_us((size_t)G4 * HH);
  u16 *Wd0ih_h = alloc_us((size_t)G4 * EPAD), *Wd0ih_l = alloc_us((size_t)G4 * EPAD);
  u16 *Wd0hh_h = alloc_us((size_t)G4 * HH),   *Wd0hh_l = alloc_us((size_t)G4 * HH);
  u16 *Wd1ih_h = alloc_us((size_t)G4 * HH),   *Wd1ih_l = alloc_us((size_t)G4 * HH);
  u16 *Wd1hh_h = alloc_us((size_t)G4 * HH),   *Wd1hh_l = alloc_us((size_t)G4 * HH);
  u16 *Wfc_h   = alloc_us((size_t)NFC * HH),  *Wfc_l   = alloc_us((size_t)NFC * HH);
  u16 *Wc_h    = alloc_us((size_t)G4 * HH),   *Wc_l    = alloc_us((size_t)G4 * HH);
  float* be0 = alloc_f(G4);
  float* be1 = alloc_f(G4);
  float* bd0 = alloc_f(G4);
  float* bd1 = alloc_f(G4);
  float* bfc = alloc_f(NFC);
  float* bd0c = alloc_f(G4);
  float* Gp0 = alloc_f((size_t)BB * G4);
  float* Gp1 = alloc_f((size_t)BB * G4);
  // zero-init region: h0[0], h1[0] (hi+lo) then c0, c1 — zeroed inside prep_all
  u16* h0h[2]; u16* h0l[2]; u16* h1h[2]; u16* h1l[2];
  h0h[0] = alloc_us((size_t)BB * HH); h0l[0] = alloc_us((size_t)BB * HH);
  h1h[0] = alloc_us((size_t)BB * HH); h1l[0] = alloc_us((size_t)BB * HH);
  float* c0 = alloc_f((size_t)BB * HH);
  float* c1 = alloc_f((size_t)BB * HH);
  h0h[1] = alloc_us((size_t)BB * HH); h0l[1] = alloc_us((size_t)BB * HH);
  h1h[1] = alloc_us((size_t)BB * HH); h1l[1] = alloc_us((size_t)BB * HH);
  u16* inph = alloc_us((size_t)BB * EPAD);
  u16* inpl = alloc_us((size_t)BB * EPAD);
  u16* Xench = alloc_us((size_t)TT * BB * EPAD);
  u16* Xencl = alloc_us((size_t)TT * BB * EPAD);
  u16* histh = alloc_us((size_t)PP * BB * HH);
  u16* histl = alloc_us((size_t)PP * BB * HH);

  // prep: ONE fused launch (splits ∥ wcomb ∥ misc ∥ state-zero — all independent)
  {
    SJobs js = {{
      { e_Wih0, We0ih_h, We0ih_l, G4, EE, G4, EPAD },
      { e_Whh0, We0hh_h, We0hh_l, G4, HH, G4, HH },
      { e_Wih1, We1ih_h, We1ih_l, G4, HH, G4, HH },
      { e_Whh1, We1hh_h, We1hh_l, G4, HH, G4, HH },
      { d_Wih0, Wd0ih_h, Wd0ih_l, G4, EE, G4, EPAD },
      { d_Whh0, Wd0hh_h, Wd0hh_l, G4, HH, G4, HH },
      { d_Wih1, Wd1ih_h, Wd1ih_l, G4, HH, G4, HH },
      { d_Whh1, Wd1hh_h, Wd1hh_l, G4, HH, G4, HH },
      { fc_W,   Wfc_h,   Wfc_l,   CC, HH, NFC, HH },
    }};
    const size_t zbytes = (size_t)4 * BB * HH * sizeof(u16) + (size_t)2 * BB * HH * sizeof(float);
    const int zn16 = (int)(zbytes / 16);
    prep_all<<<5632, 256, 0, stream>>>(
        js,
        d_Wih0, fc_W, d_bih0, d_bhh0, fc_b, Wc_h, Wc_l, bd0c,
        e_bih0, e_bhh0, be0, e_bih1, e_bhh1, be1,
        bd0, d_bih1, d_bhh1, bd1, bfc,
        x_enc, inph, inpl, Xench, Xencl,
        (unsigned*)h0h[0], zn16);
  }

  // encoder: fused pipeline, iteration t runs cell0(t) and cell1(t-1); M=64, 512 blocks, 2/CU.
  // t==TT folds the decoder-prologue partial (Gp0 = h0_final @ Wd0hh) into the idle cell0 half.
  for (int t = 0; t <= TT; ++t){
    const int rd = t & 1, wrp = (t + 1) & 1;
    const size_t ts = (size_t)(t < TT ? t : 0) * BB * EPAD;
    lstm_pair<<<512, 256, LSTM_SMEM, stream>>>(
        (t < TT) ? 1 : 0, Xench + ts, Xencl + ts,
        We0ih_h, We0ih_l, We0hh_h, We0hh_l, be0,
        h0h[rd], h0l[rd], h0h[wrp], h0l[wrp], c0,
        (t > 0) ? 1 : 0, h0h[rd], h0l[rd],
        We1ih_h, We1ih_l, We1hh_h, We1hh_l, be1,
        h1h[wrp], h1l[wrp], h1h[rd], h1l[rd], c1,
        (t == TT) ? 1 : 0, Wd0hh_h, Wd0hh_l, Gp0);
  }
  // encoder finals land at parity 0 for both h0 and h1; Gp0 ready

  // decoder: split-overlap schedule (round-5/7 proven).
  // A(p)={fin0 (K=512/EPAD, +Gp0)} ∥ {part1: h1(p-1)@Wd1hh -> Gp1}
  // B(p)={fin1 (K=512, +Gp1), writes hist[p]} ∥ {part0: h0(p)@Wd0hh -> Gp0}
  const size_t S = (size_t)BB * HH;
  for (int p = 0; p < PP; ++p){
    const u16* hp_h = p ? histh + (size_t)(p - 1) * S : h1h[0];
    const u16* hp_l = p ? histl + (size_t)(p - 1) * S : h1l[0];
    dec_ab<<<512, 256, LSTM_SMEM, stream>>>(
        p ? hp_h : inph, p ? hp_l : inpl, p ? HH : EPAD,
        p ? Wc_h : Wd0ih_h, p ? Wc_l : Wd0ih_l,
        p ? bd0c : bd0, Gp0,
        h0h[1], h0l[1], c0,
        hp_h, hp_l, Wd1hh_h, Wd1hh_l, Gp1);
    dec_ab<<<512, 256, LSTM_SMEM, stream>>>(
        h0h[1], h0l[1], HH,
        Wd1ih_h, Wd1ih_l,
        bd1, Gp1,
        histh + (size_t)p * S, histl + (size_t)p * S, c1,
        h0h[1], h0l[1], Wd0hh_h, Wd0hh_l, Gp0);
  }

  // batched FC over all 96 decoder steps
  fc_batch<<<dim3((PP * BB) / 128, NFC / 64), 256, FC_SMEM, stream>>>(
      histh, histl, Wfc_h, Wfc_l, bfc, (float*)d_out);
}